// Round 1
// baseline (971.110 us; speedup 1.0000x reference)
//
#include <hip/hip_runtime.h>
#include <math.h>

namespace {
constexpr int NN  = 12;    // nodes per graph
constexpr int FIN = 128;   // input feature dim
constexpr int H1  = 4;     // heads, layer 1
constexpr int D1  = 256;   // H1 * 64 (concat dim)
constexpr int C2  = 64;    // hidden dim layer 2
constexpr float SLOPE = 0.2f;

__device__ __forceinline__ float elu1(float x) { return x > 0.0f ? x : expm1f(x); }
}

__global__ __launch_bounds__(256, 4) void gat_fused(
    const float* __restrict__ x_in,    // [B,12,128]
    const float* __restrict__ W1,      // [128,4,64] -> [128][256]
    const float* __restrict__ a_src1,  // [4,64]
    const float* __restrict__ a_dst1,  // [4,64]
    const float* __restrict__ b1,      // [256]
    const float* __restrict__ W2,      // [256,1,64] -> [256][64]
    const float* __restrict__ a_src2,  // [64]
    const float* __restrict__ a_dst2,  // [64]
    const float* __restrict__ b2,      // [64]
    const float* __restrict__ Wc1,     // [64,32]
    const float* __restrict__ bc1,     // [32]
    const float* __restrict__ Wc2,     // [32,1]
    const float* __restrict__ bc2,     // [1]
    float* __restrict__ out)           // [B,1]
{
    __shared__ union {
        float x_l[NN][FIN];                                  // stage A: input
        struct { float h2[NN][C2]; float x3[NN][C2]; } s2;   // stage B: layer 2
    } u;
    __shared__ float h1[NN][D1];
    __shared__ float x2[NN][D1];
    __shared__ float alpha1[NN][NN][H1];   // [i][j][h]
    __shared__ float e_s1[NN][H1];
    __shared__ float e_d1[NN][H1];
    __shared__ float e_s2[NN];
    __shared__ float e_d2[NN];
    __shared__ float alpha2[NN][NN];
    __shared__ float g[C2];
    __shared__ float hdn[32];

    const int b = blockIdx.x;
    const int t = threadIdx.x;
    const float* xb = x_in + (size_t)b * (NN * FIN);

    // ---- stage input graph into LDS (coalesced)
    for (int i = t; i < NN * FIN; i += 256)
        (&u.x_l[0][0])[i] = xb[i];
    __syncthreads();

    // ---- layer 1 GEMM: h1[n][o] = sum_f x[n][f] * W1[f][o]
    // thread covers 6 nodes x 2 columns; x broadcast from LDS, W1 coalesced from L2.
    {
        const int o0 = (t & 127) * 2;
        const int n0 = (t >> 7) * 6;
        float acc[6][2];
        #pragma unroll
        for (int i = 0; i < 6; ++i) { acc[i][0] = 0.f; acc[i][1] = 0.f; }
        for (int f = 0; f < FIN; f += 4) {
            float4 xv[6];
            #pragma unroll
            for (int i = 0; i < 6; ++i)
                xv[i] = *(const float4*)&u.x_l[n0 + i][f];
            #pragma unroll
            for (int k = 0; k < 4; ++k) {
                const float2 w = *(const float2*)&W1[(f + k) * D1 + o0];
                #pragma unroll
                for (int i = 0; i < 6; ++i) {
                    const float xs = ((const float*)&xv[i])[k];
                    acc[i][0] = fmaf(xs, w.x, acc[i][0]);
                    acc[i][1] = fmaf(xs, w.y, acc[i][1]);
                }
            }
        }
        #pragma unroll
        for (int i = 0; i < 6; ++i) {
            h1[n0 + i][o0]     = acc[i][0];
            h1[n0 + i][o0 + 1] = acc[i][1];
        }
    }
    __syncthreads();

    // ---- attention logits contributions (48 dot products of length 64)
    if (t < NN * H1) {
        const int n = t >> 2, h = t & 3;
        float es = 0.f, ed = 0.f;
        #pragma unroll 8
        for (int c = 0; c < 64; ++c) {
            const float v = h1[n][h * 64 + c];
            es = fmaf(v, a_src1[h * 64 + c], es);
            ed = fmaf(v, a_dst1[h * 64 + c], ed);
        }
        e_s1[n][h] = es;
        e_d1[n][h] = ed;
    }
    __syncthreads();

    // ---- softmax over neighbors j per (i,h)
    if (t < NN * H1) {
        const int i = t >> 2, h = t & 3;
        const float edi = e_d1[i][h];
        float l[NN]; float m = -1e30f;
        #pragma unroll
        for (int j = 0; j < NN; ++j) {
            float v = edi + e_s1[j][h];
            v = v > 0.f ? v : SLOPE * v;   // leaky_relu
            l[j] = v; m = fmaxf(m, v);
        }
        float s = 0.f;
        #pragma unroll
        for (int j = 0; j < NN; ++j) { l[j] = expf(l[j] - m); s += l[j]; }
        const float inv = 1.f / s;
        #pragma unroll
        for (int j = 0; j < NN; ++j) alpha1[i][j][h] = l[j] * inv;
    }
    __syncthreads();

    // ---- aggregate + bias + ELU -> x2[i][o]
    {
        const int o = t;
        const int h = o >> 6;
        const float bo = b1[o];
        float v[NN];
        #pragma unroll
        for (int j = 0; j < NN; ++j) v[j] = h1[j][o];
        #pragma unroll
        for (int i = 0; i < NN; ++i) {
            float acc = 0.f;
            #pragma unroll
            for (int j = 0; j < NN; ++j)
                acc = fmaf(alpha1[i][j][h], v[j], acc);
            x2[i][o] = elu1(acc + bo);
        }
    }
    __syncthreads();

    // ---- layer 2 GEMM: h2[n][c] = sum_f x2[n][f] * W2[f][c]
    {
        const int c  = t & 63;
        const int n0 = (t >> 6) * 3;
        float acc[3] = {0.f, 0.f, 0.f};
        for (int f = 0; f < D1; f += 4) {
            float4 xv[3];
            #pragma unroll
            for (int i = 0; i < 3; ++i)
                xv[i] = *(const float4*)&x2[n0 + i][f];
            #pragma unroll
            for (int k = 0; k < 4; ++k) {
                const float w = W2[(f + k) * C2 + c];
                #pragma unroll
                for (int i = 0; i < 3; ++i)
                    acc[i] = fmaf(((const float*)&xv[i])[k], w, acc[i]);
            }
        }
        #pragma unroll
        for (int i = 0; i < 3; ++i)
            u.s2.h2[n0 + i][c] = acc[i];
    }
    __syncthreads();

    // ---- layer 2 attention contributions
    if (t < NN) {
        float es = 0.f, ed = 0.f;
        for (int c = 0; c < 64; c += 4) {
            const float4 v  = *(const float4*)&u.s2.h2[t][c];
            const float4 as = *(const float4*)&a_src2[c];
            const float4 ad = *(const float4*)&a_dst2[c];
            es += v.x*as.x + v.y*as.y + v.z*as.z + v.w*as.w;
            ed += v.x*ad.x + v.y*ad.y + v.z*ad.z + v.w*ad.w;
        }
        e_s2[t] = es; e_d2[t] = ed;
    }
    __syncthreads();

    if (t < NN) {
        const float edi = e_d2[t];
        float l[NN]; float m = -1e30f;
        #pragma unroll
        for (int j = 0; j < NN; ++j) {
            float v = edi + e_s2[j];
            v = v > 0.f ? v : SLOPE * v;
            l[j] = v; m = fmaxf(m, v);
        }
        float s = 0.f;
        #pragma unroll
        for (int j = 0; j < NN; ++j) { l[j] = expf(l[j] - m); s += l[j]; }
        const float inv = 1.f / s;
        #pragma unroll
        for (int j = 0; j < NN; ++j) alpha2[t][j] = l[j] * inv;
    }
    __syncthreads();

    // ---- aggregate2 + b2 + ELU -> x3 (single head, mean over heads = identity)
    {
        const int c  = t & 63;
        const int i0 = (t >> 6) * 3;
        float v[NN];
        #pragma unroll
        for (int j = 0; j < NN; ++j) v[j] = u.s2.h2[j][c];
        const float bc = b2[c];
        #pragma unroll
        for (int ii = 0; ii < 3; ++ii) {
            const int i = i0 + ii;
            float acc = 0.f;
            #pragma unroll
            for (int j = 0; j < NN; ++j)
                acc = fmaf(alpha2[i][j], v[j], acc);
            u.s2.x3[i][c] = elu1(acc + bc);
        }
    }
    __syncthreads();

    // ---- global mean pool over nodes
    if (t < C2) {
        float s = 0.f;
        #pragma unroll
        for (int i = 0; i < NN; ++i) s += u.s2.x3[i][t];
        g[t] = s * (1.0f / NN);
    }
    __syncthreads();

    // ---- classifier: 64 -> 32 (relu) -> 1
    if (t < 32) {
        float acc = bc1[t];
        #pragma unroll 8
        for (int c = 0; c < C2; ++c)
            acc = fmaf(g[c], Wc1[c * 32 + t], acc);
        hdn[t] = fmaxf(acc, 0.f);
    }
    __syncthreads();
    if (t == 0) {
        float acc = bc2[0];
        #pragma unroll
        for (int k = 0; k < 32; ++k)
            acc = fmaf(hdn[k], Wc2[k], acc);
        out[b] = acc;
    }
}

extern "C" void kernel_launch(void* const* d_in, const int* in_sizes, int n_in,
                              void* d_out, int out_size, void* d_ws, size_t ws_size,
                              hipStream_t stream) {
    const float* x     = (const float*)d_in[0];
    const float* W1    = (const float*)d_in[1];
    const float* as1   = (const float*)d_in[2];
    const float* ad1   = (const float*)d_in[3];
    const float* b1    = (const float*)d_in[4];
    const float* W2    = (const float*)d_in[5];
    const float* as2   = (const float*)d_in[6];
    const float* ad2   = (const float*)d_in[7];
    const float* b2    = (const float*)d_in[8];
    const float* Wc1   = (const float*)d_in[9];
    const float* bc1   = (const float*)d_in[10];
    const float* Wc2   = (const float*)d_in[11];
    const float* bc2   = (const float*)d_in[12];
    float* out = (float*)d_out;

    const int B = in_sizes[0] / (NN * FIN);
    gat_fused<<<dim3(B), dim3(256), 0, stream>>>(
        x, W1, as1, ad1, b1, W2, as2, ad2, b2, Wc1, bc1, Wc2, bc2, out);
}

// Round 2
// 334.026 us; speedup vs baseline: 2.9073x; 2.9073x over previous
//
#include <hip/hip_runtime.h>
#include <math.h>

typedef __attribute__((ext_vector_type(8))) short bf16x8;
typedef __attribute__((ext_vector_type(4))) float f32x4;

namespace {
constexpr int NN  = 12;
constexpr int FIN = 128;
constexpr int D1  = 256;
constexpr int C2  = 64;
constexpr float SLOPE = 0.2f;
constexpr int H1STRIDE = 536;   // bytes per h1 row (268 bf16), padded to kill write conflicts

__device__ __forceinline__ unsigned short f2bf(float f) {
    unsigned u = __builtin_bit_cast(unsigned, f);
    u += 0x7FFFu + ((u >> 16) & 1u);     // RNE
    return (unsigned short)(u >> 16);
}
__device__ __forceinline__ float bf2f(unsigned short h) {
    unsigned u = (unsigned)h << 16;
    return __builtin_bit_cast(float, u);
}
__device__ __forceinline__ float elu1(float x) { return x > 0.f ? x : expm1f(x); }
__device__ __forceinline__ float lrelu(float x) { return x > 0.f ? x : SLOPE * x; }
}

// ---------------------------------------------------------------------------
// Pack W1 [128][256] and W2 [256][64] (f32) into bf16 MFMA B-fragment layout:
//   frag(kt, nt): lane l, elem i  <-  W[k = kt*32 + (l>>4)*8 + i][c = nt*16 + (l&15)]
// stored contiguously so the main kernel loads 16 B/lane coalesced.
// ---------------------------------------------------------------------------
__global__ void prep_weights(const float* __restrict__ W1, const float* __restrict__ W2,
                             unsigned short* __restrict__ wsB1, unsigned short* __restrict__ wsB2) {
    int t = blockIdx.x * 256 + threadIdx.x;
    if (t < 32768) {                       // B1: kt<4, nt<16 : idx = ((kt*16+nt)*64 + l)*8 + i
        int i = t & 7, l = (t >> 3) & 63, kn = t >> 9;
        int kt = kn >> 4, nt = kn & 15;
        int k = kt * 32 + (l >> 4) * 8 + i;
        int c = nt * 16 + (l & 15);
        wsB1[t] = f2bf(W1[k * 256 + c]);
    } else if (t < 49152) {                // B2: kt<8, nt<4 : idx = ((kt*4+nt)*64 + l)*8 + i
        int t2 = t - 32768;
        int i = t2 & 7, l = (t2 >> 3) & 63, kn = t2 >> 9;
        int kt = kn >> 2, nt = kn & 3;
        int k = kt * 32 + (l >> 4) * 8 + i;
        int c = nt * 16 + (l & 15);
        wsB2[t2] = f2bf(W2[k * 64 + c]);
    }
}

// ---------------------------------------------------------------------------
// Main fused kernel: 4 graphs (48 rows) per block, 256 threads (4 waves).
// ---------------------------------------------------------------------------
__global__ __launch_bounds__(256, 2) void gat_mfma(
    const float* __restrict__ x_in,
    const unsigned short* __restrict__ wsB1,
    const unsigned short* __restrict__ wsB2,
    const float* __restrict__ a_src1, const float* __restrict__ a_dst1,
    const float* __restrict__ b1,
    const float* __restrict__ a_src2, const float* __restrict__ a_dst2,
    const float* __restrict__ b2,
    const float* __restrict__ Wc1, const float* __restrict__ bc1,
    const float* __restrict__ Wc2, const float* __restrict__ bc2,
    float* __restrict__ out)
{
    __shared__ __align__(16) unsigned char sA[12288];          // x bf16 [48][128] swizzled; later alpha1 f32 [4h][4g][12][12]
    __shared__ __align__(16) unsigned char sH1[48 * H1STRIDE]; // h1 bf16 [48][256]+pad; later h2 f32 [48][66]
    __shared__ __align__(16) unsigned char sX2[48 * 512];      // x2 bf16 [48][256] swizzled
    __shared__ float eS1[48][4], eD1[48][4];
    __shared__ float ePs[4][48], ePd[4][48];
    __shared__ float eS2[48], eD2[48];
    __shared__ __align__(16) float alpha2s[48][12];
    __shared__ float gpool[4][64];

    const int b = blockIdx.x, t = threadIdx.x;
    const int w = t >> 6, l = t & 63;
    const int l15 = l & 15, lq = l >> 4;

    // ---- phase 0: stage x (f32 global -> bf16 LDS, swizzled)
    {
        const float4* xs = (const float4*)(x_in + (size_t)b * (4 * NN * FIN));
        #pragma unroll
        for (int it = 0; it < 6; ++it) {
            int q = t + 256 * it;                 // 1536 float4 per block
            float4 v = xs[q];
            int e0 = q << 2, r = e0 >> 7, k = e0 & 127;
            int addr = ((r << 8) + (k << 1)) ^ ((r & 7) << 4);
            unsigned p0 = (unsigned)f2bf(v.x) | ((unsigned)f2bf(v.y) << 16);
            unsigned p1 = (unsigned)f2bf(v.z) | ((unsigned)f2bf(v.w) << 16);
            *(uint2*)(sA + addr) = make_uint2(p0, p1);
        }
    }
    __syncthreads();

    // ---- phase 1: GEMM1 (MFMA) + e_src1/e_dst1 dots from accumulators + h1 store
    {
        bf16x8 Bf[4][4];
        const uint4* pb = (const uint4*)wsB1;
        #pragma unroll
        for (int ng = 0; ng < 4; ++ng)
            #pragma unroll
            for (int kt = 0; kt < 4; ++kt)
                Bf[ng][kt] = __builtin_bit_cast(bf16x8, pb[(kt * 16 + (w * 4 + ng)) * 64 + l]);
        float as1v[4], ad1v[4];
        #pragma unroll
        for (int ng = 0; ng < 4; ++ng) {
            int c = w * 64 + ng * 16 + l15;
            as1v[ng] = a_src1[c]; ad1v[ng] = a_dst1[c];
        }
        for (int m = 0; m < 3; ++m) {
            int r = m * 16 + l15;
            int abase = (r << 8) + (lq << 4);
            int swz = (r & 7) << 4;
            bf16x8 Af[4];
            #pragma unroll
            for (int kt = 0; kt < 4; ++kt)
                Af[kt] = *(const bf16x8*)(sA + ((abase + (kt << 6)) ^ swz));
            f32x4 acc[4];
            #pragma unroll
            for (int ng = 0; ng < 4; ++ng) acc[ng] = (f32x4){0.f, 0.f, 0.f, 0.f};
            #pragma unroll
            for (int ng = 0; ng < 4; ++ng)
                #pragma unroll
                for (int kt = 0; kt < 4; ++kt)
                    acc[ng] = __builtin_amdgcn_mfma_f32_16x16x32_bf16(Af[kt], Bf[ng][kt], acc[ng], 0, 0, 0);
            #pragma unroll
            for (int reg = 0; reg < 4; ++reg) {
                float es = 0.f, ed = 0.f;
                #pragma unroll
                for (int ng = 0; ng < 4; ++ng) {
                    es = fmaf(acc[ng][reg], as1v[ng], es);
                    ed = fmaf(acc[ng][reg], ad1v[ng], ed);
                }
                #pragma unroll
                for (int msk = 1; msk < 16; msk <<= 1) {
                    es += __shfl_xor(es, msk);
                    ed += __shfl_xor(ed, msk);
                }
                if (l15 == 0) {
                    int row = m * 16 + lq * 4 + reg;
                    eS1[row][w] = es; eD1[row][w] = ed;
                }
            }
            #pragma unroll
            for (int ng = 0; ng < 4; ++ng)
                #pragma unroll
                for (int reg = 0; reg < 4; ++reg) {
                    int row = m * 16 + lq * 4 + reg;
                    int col = w * 64 + ng * 16 + l15;
                    *(unsigned short*)(sH1 + row * H1STRIDE + (col << 1)) = f2bf(acc[ng][reg]);
                }
        }
    }
    __syncthreads();

    // ---- phase 2: softmax over neighbors, layer 1 (192 items: 4g x 12i x 4h)
    if (t < 192) {
        int g = t / 48, rem = t % 48, i = rem >> 2, h = rem & 3;
        float edi = eD1[g * NN + i][h];
        float lv[12]; float mx = -1e30f;
        #pragma unroll
        for (int j = 0; j < 12; ++j) {
            float v = lrelu(edi + eS1[g * NN + j][h]);
            lv[j] = v; mx = fmaxf(mx, v);
        }
        float s = 0.f;
        #pragma unroll
        for (int j = 0; j < 12; ++j) { lv[j] = __expf(lv[j] - mx); s += lv[j]; }
        float inv = 1.f / s;
        float* al = (float*)sA + ((h * 4 + g) * 12 + i) * 12;   // [h][g][i][j], j contiguous
        #pragma unroll
        for (int j = 0; j < 12; ++j) al[j] = lv[j] * inv;
    }
    __syncthreads();

    // ---- phase 3: aggregate1 + bias + ELU -> x2 bf16 (swizzled)
    {
        int o = t, h = w;                    // wave w covers cols of head w
        float bo = b1[o];
        const float4* alb = (const float4*)sA;
        for (int g = 0; g < 4; ++g) {
            float v[12];
            #pragma unroll
            for (int j = 0; j < 12; ++j)
                v[j] = bf2f(*(const unsigned short*)(sH1 + (g * NN + j) * H1STRIDE + (o << 1)));
            #pragma unroll
            for (int i = 0; i < 12; ++i) {
                int base = ((h * 4 + g) * 12 + i) * 3;
                float4 a0 = alb[base], a1 = alb[base + 1], a2 = alb[base + 2];
                float accv = a0.x * v[0] + a0.y * v[1] + a0.z * v[2] + a0.w * v[3]
                           + a1.x * v[4] + a1.y * v[5] + a1.z * v[6] + a1.w * v[7]
                           + a2.x * v[8] + a2.y * v[9] + a2.z * v[10] + a2.w * v[11];
                float val = elu1(accv + bo);
                int row = g * NN + i;
                int addr = ((row << 9) + (o << 1)) ^ ((row & 7) << 4);
                *(unsigned short*)(sX2 + addr) = f2bf(val);
            }
        }
    }
    __syncthreads();

    // ---- phase 4: GEMM2 (MFMA) + partial e2 dots + h2 f32 store
    {
        bf16x8 B2f[8];
        const uint4* pb2 = (const uint4*)wsB2;
        #pragma unroll
        for (int kt = 0; kt < 8; ++kt)
            B2f[kt] = __builtin_bit_cast(bf16x8, pb2[(kt * 4 + w) * 64 + l]);
        int c = w * 16 + l15;
        float as2v = a_src2[c], ad2v = a_dst2[c];
        float* h2 = (float*)sH1;
        for (int m = 0; m < 3; ++m) {
            int r = m * 16 + l15;
            int abase = (r << 9) + (lq << 4);
            int swz = (r & 7) << 4;
            f32x4 acc = {0.f, 0.f, 0.f, 0.f};
            #pragma unroll
            for (int kt = 0; kt < 8; ++kt) {
                bf16x8 Af = *(const bf16x8*)(sX2 + ((abase + (kt << 6)) ^ swz));
                acc = __builtin_amdgcn_mfma_f32_16x16x32_bf16(Af, B2f[kt], acc, 0, 0, 0);
            }
            #pragma unroll
            for (int reg = 0; reg < 4; ++reg) {
                float es = acc[reg] * as2v, ed = acc[reg] * ad2v;
                #pragma unroll
                for (int msk = 1; msk < 16; msk <<= 1) {
                    es += __shfl_xor(es, msk);
                    ed += __shfl_xor(ed, msk);
                }
                int row = m * 16 + lq * 4 + reg;
                if (l15 == 0) { ePs[w][row] = es; ePd[w][row] = ed; }
                h2[row * 66 + c] = acc[reg];
            }
        }
    }
    __syncthreads();

    // ---- phase 5: reduce e2 partials across waves, then softmax2
    if (t < 48) {
        eS2[t] = ePs[0][t] + ePs[1][t] + ePs[2][t] + ePs[3][t];
        eD2[t] = ePd[0][t] + ePd[1][t] + ePd[2][t] + ePd[3][t];
    }
    __syncthreads();
    if (t < 48) {
        int g = t / NN;
        float edi = eD2[t];
        float lv[12]; float mx = -1e30f;
        #pragma unroll
        for (int j = 0; j < 12; ++j) {
            float v = lrelu(edi + eS2[g * NN + j]);
            lv[j] = v; mx = fmaxf(mx, v);
        }
        float s = 0.f;
        #pragma unroll
        for (int j = 0; j < 12; ++j) { lv[j] = __expf(lv[j] - mx); s += lv[j]; }
        float inv = 1.f / s;
        #pragma unroll
        for (int j = 0; j < 12; ++j) alpha2s[t][j] = lv[j] * inv;
    }
    __syncthreads();

    // ---- phase 6: aggregate2 + bias + ELU + mean-pool (x3 never materialized)
    {
        int o = t & 63, g = t >> 6;
        const float* h2 = (const float*)sH1;
        float v[12];
        #pragma unroll
        for (int j = 0; j < 12; ++j) v[j] = h2[(g * NN + j) * 66 + o];
        float bo = b2[o], gsum = 0.f;
        #pragma unroll
        for (int i = 0; i < 12; ++i) {
            const float4* ap = (const float4*)(&alpha2s[0][0] + (g * NN + i) * 12);
            float4 a0 = ap[0], a1 = ap[1], a2 = ap[2];
            float accv = a0.x * v[0] + a0.y * v[1] + a0.z * v[2] + a0.w * v[3]
                       + a1.x * v[4] + a1.y * v[5] + a1.z * v[6] + a1.w * v[7]
                       + a2.x * v[8] + a2.y * v[9] + a2.z * v[10] + a2.w * v[11];
            gsum += elu1(accv + bo);
        }
        gpool[g][o] = gsum * (1.0f / 12.0f);
    }
    __syncthreads();

    // ---- phase 7: classifier 64 -> 32 (relu) -> 1, wave-reduced
    if (t < 128) {
        int g = t >> 5, nr = t & 31;
        float acc = bc1[nr];
        #pragma unroll
        for (int cc = 0; cc < 64; ++cc)
            acc = fmaf(gpool[g][cc], Wc1[cc * 32 + nr], acc);
        float val = fmaxf(acc, 0.f) * Wc2[nr];
        #pragma unroll
        for (int msk = 1; msk < 32; msk <<= 1) val += __shfl_xor(val, msk);
        if (nr == 0) out[b * 4 + g] = val + bc2[0];
    }
}

// ---------------------------------------------------------------------------
// f32 fallback (round-1 kernel) — used only if ws too small or B % 4 != 0
// ---------------------------------------------------------------------------
__global__ __launch_bounds__(256, 4) void gat_fused_f32(
    const float* __restrict__ x_in, const float* __restrict__ W1,
    const float* __restrict__ a_src1, const float* __restrict__ a_dst1,
    const float* __restrict__ b1, const float* __restrict__ W2,
    const float* __restrict__ a_src2, const float* __restrict__ a_dst2,
    const float* __restrict__ b2, const float* __restrict__ Wc1,
    const float* __restrict__ bc1, const float* __restrict__ Wc2,
    const float* __restrict__ bc2, float* __restrict__ out)
{
    __shared__ union {
        float x_l[NN][FIN];
        struct { float h2[NN][C2]; float x3[NN][C2]; } s2;
    } u;
    __shared__ float h1s[NN][D1];
    __shared__ float x2s[NN][D1];
    __shared__ float alpha1[NN][NN][4];
    __shared__ float e_s1[NN][4], e_d1[NN][4];
    __shared__ float e_s2[NN], e_d2[NN];
    __shared__ float alpha2[NN][NN];
    __shared__ float gph[C2];
    __shared__ float hdn[32];

    const int b = blockIdx.x, t = threadIdx.x;
    const float* xb = x_in + (size_t)b * (NN * FIN);
    for (int i = t; i < NN * FIN; i += 256) (&u.x_l[0][0])[i] = xb[i];
    __syncthreads();
    {
        const int o0 = (t & 127) * 2, n0 = (t >> 7) * 6;
        float acc[6][2];
        #pragma unroll
        for (int i = 0; i < 6; ++i) { acc[i][0] = 0.f; acc[i][1] = 0.f; }
        for (int f = 0; f < FIN; f += 4) {
            float4 xv[6];
            #pragma unroll
            for (int i = 0; i < 6; ++i) xv[i] = *(const float4*)&u.x_l[n0 + i][f];
            #pragma unroll
            for (int k = 0; k < 4; ++k) {
                const float2 wv = *(const float2*)&W1[(f + k) * D1 + o0];
                #pragma unroll
                for (int i = 0; i < 6; ++i) {
                    const float xs = ((const float*)&xv[i])[k];
                    acc[i][0] = fmaf(xs, wv.x, acc[i][0]);
                    acc[i][1] = fmaf(xs, wv.y, acc[i][1]);
                }
            }
        }
        #pragma unroll
        for (int i = 0; i < 6; ++i) { h1s[n0+i][o0] = acc[i][0]; h1s[n0+i][o0+1] = acc[i][1]; }
    }
    __syncthreads();
    if (t < NN * 4) {
        const int n = t >> 2, h = t & 3;
        float es = 0.f, ed = 0.f;
        for (int c = 0; c < 64; ++c) {
            const float v = h1s[n][h * 64 + c];
            es = fmaf(v, a_src1[h * 64 + c], es);
            ed = fmaf(v, a_dst1[h * 64 + c], ed);
        }
        e_s1[n][h] = es; e_d1[n][h] = ed;
    }
    __syncthreads();
    if (t < NN * 4) {
        const int i = t >> 2, h = t & 3;
        const float edi = e_d1[i][h];
        float lv[NN]; float m = -1e30f;
        #pragma unroll
        for (int j = 0; j < NN; ++j) {
            float v = edi + e_s1[j][h]; v = v > 0.f ? v : SLOPE * v;
            lv[j] = v; m = fmaxf(m, v);
        }
        float s = 0.f;
        #pragma unroll
        for (int j = 0; j < NN; ++j) { lv[j] = __expf(lv[j] - m); s += lv[j]; }
        const float inv = 1.f / s;
        #pragma unroll
        for (int j = 0; j < NN; ++j) alpha1[i][j][h] = lv[j] * inv;
    }
    __syncthreads();
    {
        const int o = t, h = o >> 6;
        const float bo = b1[o];
        float v[NN];
        #pragma unroll
        for (int j = 0; j < NN; ++j) v[j] = h1s[j][o];
        #pragma unroll
        for (int i = 0; i < NN; ++i) {
            float acc = 0.f;
            #pragma unroll
            for (int j = 0; j < NN; ++j) acc = fmaf(alpha1[i][j][h], v[j], acc);
            x2s[i][o] = elu1(acc + bo);
        }
    }
    __syncthreads();
    {
        const int c = t & 63, n0 = (t >> 6) * 3;
        float acc[3] = {0.f, 0.f, 0.f};
        for (int f = 0; f < D1; f += 4) {
            float4 xv[3];
            #pragma unroll
            for (int i = 0; i < 3; ++i) xv[i] = *(const float4*)&x2s[n0 + i][f];
            #pragma unroll
            for (int k = 0; k < 4; ++k) {
                const float wv = W2[(f + k) * C2 + c];
                #pragma unroll
                for (int i = 0; i < 3; ++i) acc[i] = fmaf(((const float*)&xv[i])[k], wv, acc[i]);
            }
        }
        #pragma unroll
        for (int i = 0; i < 3; ++i) u.s2.h2[n0 + i][c] = acc[i];
    }
    __syncthreads();
    if (t < NN) {
        float es = 0.f, ed = 0.f;
        for (int c = 0; c < 64; c += 4) {
            const float4 v  = *(const float4*)&u.s2.h2[t][c];
            const float4 as = *(const float4*)&a_src2[c];
            const float4 ad = *(const float4*)&a_dst2[c];
            es += v.x*as.x + v.y*as.y + v.z*as.z + v.w*as.w;
            ed += v.x*ad.x + v.y*ad.y + v.z*ad.z + v.w*ad.w;
        }
        e_s2[t] = es; e_d2[t] = ed;
    }
    __syncthreads();
    if (t < NN) {
        const float edi = e_d2[t];
        float lv[NN]; float m = -1e30f;
        #pragma unroll
        for (int j = 0; j < NN; ++j) {
            float v = edi + e_s2[j]; v = v > 0.f ? v : SLOPE * v;
            lv[j] = v; m = fmaxf(m, v);
        }
        float s = 0.f;
        #pragma unroll
        for (int j = 0; j < NN; ++j) { lv[j] = __expf(lv[j] - m); s += lv[j]; }
        const float inv = 1.f / s;
        #pragma unroll
        for (int j = 0; j < NN; ++j) alpha2[t][j] = lv[j] * inv;
    }
    __syncthreads();
    {
        const int c = t & 63, i0 = (t >> 6) * 3;
        float v[NN];
        #pragma unroll
        for (int j = 0; j < NN; ++j) v[j] = u.s2.h2[j][c];
        const float bc = b2[c];
        #pragma unroll
        for (int ii = 0; ii < 3; ++ii) {
            const int i = i0 + ii;
            float acc = 0.f;
            #pragma unroll
            for (int j = 0; j < NN; ++j) acc = fmaf(alpha2[i][j], v[j], acc);
            u.s2.x3[i][c] = elu1(acc + bc);
        }
    }
    __syncthreads();
    if (t < C2) {
        float s = 0.f;
        #pragma unroll
        for (int i = 0; i < NN; ++i) s += u.s2.x3[i][t];
        gph[t] = s * (1.0f / NN);
    }
    __syncthreads();
    if (t < 32) {
        float acc = bc1[t];
        for (int c = 0; c < C2; ++c) acc = fmaf(gph[c], Wc1[c * 32 + t], acc);
        hdn[t] = fmaxf(acc, 0.f);
    }
    __syncthreads();
    if (t == 0) {
        float acc = bc2[0];
        #pragma unroll
        for (int k = 0; k < 32; ++k) acc = fmaf(hdn[k], Wc2[k], acc);
        out[b] = acc;
    }
}

extern "C" void kernel_launch(void* const* d_in, const int* in_sizes, int n_in,
                              void* d_out, int out_size, void* d_ws, size_t ws_size,
                              hipStream_t stream) {
    const float* x   = (const float*)d_in[0];
    const float* W1  = (const float*)d_in[1];
    const float* as1 = (const float*)d_in[2];
    const float* ad1 = (const float*)d_in[3];
    const float* b1  = (const float*)d_in[4];
    const float* W2  = (const float*)d_in[5];
    const float* as2 = (const float*)d_in[6];
    const float* ad2 = (const float*)d_in[7];
    const float* b2  = (const float*)d_in[8];
    const float* Wc1 = (const float*)d_in[9];
    const float* bc1 = (const float*)d_in[10];
    const float* Wc2 = (const float*)d_in[11];
    const float* bc2 = (const float*)d_in[12];
    float* out = (float*)d_out;

    const int B = in_sizes[0] / (NN * FIN);

    if (ws_size >= 98304 && (B % 4) == 0) {
        unsigned short* wsB1 = (unsigned short*)d_ws;
        unsigned short* wsB2 = wsB1 + 32768;
        prep_weights<<<192, 256, 0, stream>>>(W1, W2, wsB1, wsB2);
        gat_mfma<<<B / 4, 256, 0, stream>>>(x, wsB1, wsB2, as1, ad1, b1,
                                            as2, ad2, b2, Wc1, bc1, Wc2, bc2, out);
    } else {
        gat_fused_f32<<<B, 256, 0, stream>>>(x, W1, as1, ad1, b1, W2, as2, ad2, b2,
                                             Wc1, bc1, Wc2, bc2, out);
    }
}

// Round 3
// 230.986 us; speedup vs baseline: 4.2042x; 1.4461x over previous
//
#include <hip/hip_runtime.h>
#include <math.h>

typedef __attribute__((ext_vector_type(8))) short bf16x8;
typedef __attribute__((ext_vector_type(4))) float f32x4;

namespace {
constexpr int NN  = 12;
constexpr int FIN = 128;
constexpr int D1  = 256;
constexpr int C2  = 64;
constexpr float SLOPE = 0.2f;

__device__ __forceinline__ unsigned short f2bf(float f) {
    unsigned u = __builtin_bit_cast(unsigned, f);
    u += 0x7FFFu + ((u >> 16) & 1u);     // RNE
    return (unsigned short)(u >> 16);
}
__device__ __forceinline__ float elu1(float x) { return x > 0.f ? x : expm1f(x); }
__device__ __forceinline__ float lrelu(float x) { return x > 0.f ? x : SLOPE * x; }
}

// ---------------------------------------------------------------------------
// Pack B-operands into bf16 MFMA fragment layout, with attention-vector
// columns folded in as extra N-tiles:
//   B1: [128 K][16 tiles of W1-cols + 1 e-tile]  -> idx ((kt*17+nt)*64+l)*8+i
//       e-tile cols 0..3 = W1_h @ a_src_h, cols 4..7 = W1_h @ a_dst_h
//   B2: [256 K][4 tiles of W2-cols + 1 e-tile]   -> idx ((kt*5+nt)*64+l)*8+i
//       e-tile col 0 = W2 @ a_src2, col 1 = W2 @ a_dst2
// fragment: lane l elem i <- B[k = kt*32+(l>>4)*8+i][c = nt*16+(l&15)]
// ---------------------------------------------------------------------------
__global__ void prep_weights(const float* __restrict__ W1, const float* __restrict__ as1,
                             const float* __restrict__ ad1,
                             const float* __restrict__ W2, const float* __restrict__ as2,
                             const float* __restrict__ ad2,
                             unsigned short* __restrict__ wsB1, unsigned short* __restrict__ wsB2) {
    int t = blockIdx.x * 256 + threadIdx.x;
    if (t < 34816) {
        int i = t & 7, l = (t >> 3) & 63, kn = t >> 9;    // kn 0..67
        int kt = kn / 17, nt = kn % 17;
        int k = kt * 32 + (l >> 4) * 8 + i;
        float v = 0.f;
        if (nt < 16) {
            v = W1[k * 256 + nt * 16 + (l & 15)];
        } else {
            int cc = l & 15;
            if (cc < 4)      for (int c = 0; c < 64; ++c) v += W1[k * 256 + cc * 64 + c] * as1[cc * 64 + c];
            else if (cc < 8) for (int c = 0; c < 64; ++c) v += W1[k * 256 + (cc - 4) * 64 + c] * ad1[(cc - 4) * 64 + c];
        }
        wsB1[t] = f2bf(v);
    } else if (t < 55296) {
        int t2 = t - 34816;
        int i = t2 & 7, l = (t2 >> 3) & 63, kn = t2 >> 9; // kn 0..39
        int kt = kn / 5, nt = kn % 5;
        int k = kt * 32 + (l >> 4) * 8 + i;
        float v = 0.f;
        if (nt < 4) {
            v = W2[k * 64 + nt * 16 + (l & 15)];
        } else {
            int cc = l & 15;
            if (cc == 0)      for (int c = 0; c < 64; ++c) v += W2[k * 64 + c] * as2[c];
            else if (cc == 1) for (int c = 0; c < 64; ++c) v += W2[k * 64 + c] * ad2[c];
        }
        wsB2[t2] = f2bf(v);
    }
}

// ---------------------------------------------------------------------------
// Main fused kernel: 4 graphs (48 rows) per block, 256 threads (4 waves).
// All GEMMs AND attention aggregations on the matrix pipe.
// ---------------------------------------------------------------------------
__global__ __launch_bounds__(256, 2) void gat_mfma2(
    const float* __restrict__ x_in,
    const unsigned short* __restrict__ wsB1,
    const unsigned short* __restrict__ wsB2,
    const float* __restrict__ b1, const float* __restrict__ b2,
    const float* __restrict__ Wc1, const float* __restrict__ bc1,
    const float* __restrict__ Wc2, const float* __restrict__ bc2,
    float* __restrict__ out)
{
    // R0: x bf16 [48][128] swz (12288)           | x3 f32 [48][68] (13056)
    // R1: h1T bf16 [256 col][64 row] swz (32768) | h2T [64][64] (8192) + alphaA2 [48][64] @+8192 (6144)
    // R2: alphaA1 bf16 [4][48][64] swz (24576)   | x2 bf16 [4 head][48][64] swz (same geometry)
    __shared__ __align__(16) unsigned char R0[13056];
    __shared__ __align__(16) unsigned char R1[32768];
    __shared__ __align__(16) unsigned char R2[24576];
    __shared__ float eS1[48][4], eD1[48][4];
    __shared__ float eS2[48], eD2[48];
    __shared__ float gpool[4][64];

    const int b = blockIdx.x, t = threadIdx.x;
    const int w = t >> 6, l = t & 63, l15 = l & 15, lq = l >> 4;

    // ---- P0: stage x (f32 -> bf16 LDS swizzled) + zero-fill padding regions
    {
        const float4* xs = (const float4*)(x_in + (size_t)b * (4 * NN * FIN));
        #pragma unroll
        for (int it = 0; it < 6; ++it) {
            int q = t + 256 * it;
            float4 v = xs[q];
            int e0 = q << 2, r = e0 >> 7, k = e0 & 127;
            int addr = ((r << 8) + (k << 1)) ^ ((r & 7) << 4);
            unsigned p0 = (unsigned)f2bf(v.x) | ((unsigned)f2bf(v.y) << 16);
            unsigned p1 = (unsigned)f2bf(v.z) | ((unsigned)f2bf(v.w) << 16);
            *(uint2*)(R0 + addr) = make_uint2(p0, p1);
        }
        #pragma unroll
        for (int it = 0; it < 6; ++it)                     // zero alphaA1 (24576 B)
            *(uint4*)(R2 + ((it * 256 + t) << 4)) = make_uint4(0, 0, 0, 0);
        #pragma unroll
        for (int z = 0; z < 2; ++z) {                      // zero h1T rows 48..63
            int id = t + 256 * z;                          // 512 x 16B
            int col = id >> 1, bs = 6 + (id & 1);
            int addr = ((col << 7) + (bs << 4)) ^ ((col & 7) << 4);
            *(uint4*)(R1 + addr) = make_uint4(0, 0, 0, 0);
        }
    }
    __syncthreads();

    // ---- P1: GEMM1 (x @ [W1 | va1]) -> h1T bf16 + eS1/eD1 direct
    {
        const uint4* pb = (const uint4*)wsB1;
        bf16x8 Bf[4][4];
        #pragma unroll
        for (int ng = 0; ng < 4; ++ng)
            #pragma unroll
            for (int kt = 0; kt < 4; ++kt)
                Bf[ng][kt] = __builtin_bit_cast(bf16x8, pb[(kt * 17 + (w * 4 + ng)) * 64 + l]);
        bf16x8 Bfe[4];
        if (w == 0) {
            #pragma unroll
            for (int kt = 0; kt < 4; ++kt)
                Bfe[kt] = __builtin_bit_cast(bf16x8, pb[(kt * 17 + 16) * 64 + l]);
        }
        #pragma unroll
        for (int m = 0; m < 3; ++m) {
            int r = m * 16 + l15, abase = (r << 8) + (lq << 4), swz = (r & 7) << 4;
            bf16x8 Af[4];
            #pragma unroll
            for (int kt = 0; kt < 4; ++kt)
                Af[kt] = *(const bf16x8*)(R0 + ((abase + (kt << 6)) ^ swz));
            f32x4 acc[4];
            #pragma unroll
            for (int ng = 0; ng < 4; ++ng) acc[ng] = (f32x4){0.f, 0.f, 0.f, 0.f};
            #pragma unroll
            for (int ng = 0; ng < 4; ++ng)
                #pragma unroll
                for (int kt = 0; kt < 4; ++kt)
                    acc[ng] = __builtin_amdgcn_mfma_f32_16x16x32_bf16(Af[kt], Bf[ng][kt], acc[ng], 0, 0, 0);
            int row0 = m * 16 + lq * 4;
            #pragma unroll
            for (int ng = 0; ng < 4; ++ng) {               // packed b64 store (4 consecutive rows)
                int col = w * 64 + ng * 16 + l15;
                unsigned q0 = (unsigned)f2bf(acc[ng][0]) | ((unsigned)f2bf(acc[ng][1]) << 16);
                unsigned q1 = (unsigned)f2bf(acc[ng][2]) | ((unsigned)f2bf(acc[ng][3]) << 16);
                int addr = ((col << 7) + (row0 << 1)) ^ ((col & 7) << 4);
                *(uint2*)(R1 + addr) = make_uint2(q0, q1);
            }
            if (w == 0) {
                f32x4 acce = (f32x4){0.f, 0.f, 0.f, 0.f};
                #pragma unroll
                for (int kt = 0; kt < 4; ++kt)
                    acce = __builtin_amdgcn_mfma_f32_16x16x32_bf16(Af[kt], Bfe[kt], acce, 0, 0, 0);
                if (l15 < 8) {
                    #pragma unroll
                    for (int reg = 0; reg < 4; ++reg) {
                        int row = row0 + reg;
                        if (l15 < 4) eS1[row][l15] = acce[reg];
                        else         eD1[row][l15 - 4] = acce[reg];
                    }
                }
            }
        }
    }
    __syncthreads();

    // ---- P2: softmax1 -> alphaA1 bf16 (A-fragment layout, blockdiag)
    if (t < 192) {
        int g = t / 48, rem = t % 48, i = rem >> 2, h = rem & 3;
        int rowi = g * 12 + i;
        float edi = eD1[rowi][h];
        float lv[12]; float mx = -1e30f;
        #pragma unroll
        for (int j = 0; j < 12; ++j) {
            float v = lrelu(edi + eS1[g * 12 + j][h]);
            lv[j] = v; mx = fmaxf(mx, v);
        }
        float s = 0.f;
        #pragma unroll
        for (int j = 0; j < 12; ++j) { lv[j] = __expf(lv[j] - mx); s += lv[j]; }
        float inv = 1.f / s;
        unsigned char* base = R2 + h * 6144;
        #pragma unroll
        for (int j = 0; j < 12; ++j) {
            int k = g * 12 + j;
            int addr = ((rowi << 7) + (k << 1)) ^ ((rowi & 7) << 4);
            *(unsigned short*)(base + addr) = f2bf(lv[j] * inv);
        }
    }
    __syncthreads();

    // ---- P3: aggregation1 via MFMA (alpha1_h @ h1_h) + bias + ELU -> x2 (overlays alphaA1)
    {
        bf16x8 Bh[2][4];
        #pragma unroll
        for (int kt = 0; kt < 2; ++kt)
            #pragma unroll
            for (int nt = 0; nt < 4; ++nt) {
                int col = w * 64 + nt * 16 + l15;
                int addr = ((col << 7) + (kt << 6) + (lq << 4)) ^ ((col & 7) << 4);
                Bh[kt][nt] = *(const bf16x8*)(R1 + addr);
            }
        float b1v[4];
        #pragma unroll
        for (int nt = 0; nt < 4; ++nt) b1v[nt] = b1[w * 64 + nt * 16 + l15];
        unsigned char* aab = R2 + w * 6144;   // wave w: alpha of head w, then x2 of head w
        #pragma unroll
        for (int m = 0; m < 3; ++m) {
            int r = m * 16 + l15, swz = (r & 7) << 4;
            bf16x8 Aa[2];
            #pragma unroll
            for (int kt = 0; kt < 2; ++kt)
                Aa[kt] = *(const bf16x8*)(aab + (((r << 7) + (kt << 6) + (lq << 4)) ^ swz));
            #pragma unroll
            for (int nt = 0; nt < 4; ++nt) {
                f32x4 acc = (f32x4){0.f, 0.f, 0.f, 0.f};
                #pragma unroll
                for (int kt = 0; kt < 2; ++kt)
                    acc = __builtin_amdgcn_mfma_f32_16x16x32_bf16(Aa[kt], Bh[kt][nt], acc, 0, 0, 0);
                #pragma unroll
                for (int reg = 0; reg < 4; ++reg) {
                    int row = m * 16 + lq * 4 + reg;
                    float val = elu1(acc[reg] + b1v[nt]);
                    int addr = ((row << 7) + ((nt * 16 + l15) << 1)) ^ ((row & 7) << 4);
                    *(unsigned short*)(aab + addr) = f2bf(val);
                }
            }
        }
    }
    __syncthreads();

    // ---- P4: GEMM2 (x2 @ [W2 | va2]) -> h2T bf16 + eS2/eD2; zero h2T pad + alphaA2
    {
        if (t < 128) {                                     // zero h2T rows 48..63
            int col = t >> 1, bs = 6 + (t & 1);
            int addr = ((col << 7) + (bs << 4)) ^ ((col & 7) << 4);
            *(uint4*)(R1 + addr) = make_uint4(0, 0, 0, 0);
        }
        if (t < 192) {                                     // zero alphaA2 (6144 B)
            *(uint4*)(R1 + 8192 + (t << 4)) = make_uint4(0, 0, 0, 0);
            *(uint4*)(R1 + 8192 + ((t + 192) << 4)) = make_uint4(0, 0, 0, 0);
        }
        const uint4* pb2 = (const uint4*)wsB2;
        bf16x8 Bg[8], Be2[8];
        #pragma unroll
        for (int kt = 0; kt < 8; ++kt)
            Bg[kt] = __builtin_bit_cast(bf16x8, pb2[(kt * 5 + w) * 64 + l]);
        if (w == 0) {
            #pragma unroll
            for (int kt = 0; kt < 8; ++kt)
                Be2[kt] = __builtin_bit_cast(bf16x8, pb2[(kt * 5 + 4) * 64 + l]);
        }
        #pragma unroll
        for (int m = 0; m < 3; ++m) {
            int r = m * 16 + l15, swz = (r & 7) << 4;
            f32x4 acc = (f32x4){0.f, 0.f, 0.f, 0.f}, acce = (f32x4){0.f, 0.f, 0.f, 0.f};
            #pragma unroll
            for (int kt = 0; kt < 8; ++kt) {
                int addr = (kt >> 1) * 6144 + (((r << 7) + ((kt & 1) << 6) + (lq << 4)) ^ swz);
                bf16x8 Ax = *(const bf16x8*)(R2 + addr);
                acc = __builtin_amdgcn_mfma_f32_16x16x32_bf16(Ax, Bg[kt], acc, 0, 0, 0);
                if (w == 0) acce = __builtin_amdgcn_mfma_f32_16x16x32_bf16(Ax, Be2[kt], acce, 0, 0, 0);
            }
            int col = w * 16 + l15, row0 = m * 16 + lq * 4;
            unsigned q0 = (unsigned)f2bf(acc[0]) | ((unsigned)f2bf(acc[1]) << 16);
            unsigned q1 = (unsigned)f2bf(acc[2]) | ((unsigned)f2bf(acc[3]) << 16);
            int addr = ((col << 7) + (row0 << 1)) ^ ((col & 7) << 4);
            *(uint2*)(R1 + addr) = make_uint2(q0, q1);
            if (w == 0 && l15 < 2) {
                #pragma unroll
                for (int reg = 0; reg < 4; ++reg) {
                    int row = row0 + reg;
                    if (l15 == 0) eS2[row] = acce[reg];
                    else          eD2[row] = acce[reg];
                }
            }
        }
    }
    __syncthreads();

    // ---- P5: softmax2 -> alphaA2 bf16
    if (t < 48) {
        int g = t / 12;
        float edi = eD2[t];
        float lv[12]; float mx = -1e30f;
        #pragma unroll
        for (int j = 0; j < 12; ++j) {
            float v = lrelu(edi + eS2[g * 12 + j]);
            lv[j] = v; mx = fmaxf(mx, v);
        }
        float s = 0.f;
        #pragma unroll
        for (int j = 0; j < 12; ++j) { lv[j] = __expf(lv[j] - mx); s += lv[j]; }
        float inv = 1.f / s;
        #pragma unroll
        for (int j = 0; j < 12; ++j) {
            int k = g * 12 + j;
            int addr = 8192 + (((t << 7) + (k << 1)) ^ ((t & 7) << 4));
            *(unsigned short*)(R1 + addr) = f2bf(lv[j] * inv);
        }
    }
    __syncthreads();

    // ---- P6: aggregation2 via MFMA + bias + ELU -> x3 f32 (overlays R0)
    {
        bf16x8 Bh2[2];
        int col = w * 16 + l15;
        #pragma unroll
        for (int kt = 0; kt < 2; ++kt) {
            int addr = ((col << 7) + (kt << 6) + (lq << 4)) ^ ((col & 7) << 4);
            Bh2[kt] = *(const bf16x8*)(R1 + addr);
        }
        float b2v = b2[col];
        #pragma unroll
        for (int m = 0; m < 3; ++m) {
            int r = m * 16 + l15, swz = (r & 7) << 4;
            f32x4 acc = (f32x4){0.f, 0.f, 0.f, 0.f};
            #pragma unroll
            for (int kt = 0; kt < 2; ++kt) {
                bf16x8 Aa = *(const bf16x8*)(R1 + 8192 + (((r << 7) + (kt << 6) + (lq << 4)) ^ swz));
                acc = __builtin_amdgcn_mfma_f32_16x16x32_bf16(Aa, Bh2[kt], acc, 0, 0, 0);
            }
            #pragma unroll
            for (int reg = 0; reg < 4; ++reg) {
                int row = m * 16 + lq * 4 + reg;
                *(float*)(R0 + row * 272 + (col << 2)) = elu1(acc[reg] + b2v);
            }
        }
    }
    __syncthreads();

    // ---- pool
    {
        int o = t & 63, g = t >> 6;
        float s = 0.f;
        #pragma unroll
        for (int j = 0; j < 12; ++j)
            s += *(const float*)(R0 + (g * 12 + j) * 272 + (o << 2));
        gpool[g][o] = s * (1.0f / 12.0f);
    }
    __syncthreads();

    // ---- classifier 64 -> 32 (relu) -> 1
    if (t < 128) {
        int g = t >> 5, nr = t & 31;
        float acc = bc1[nr];
        #pragma unroll
        for (int cc = 0; cc < 64; ++cc)
            acc = fmaf(gpool[g][cc], Wc1[cc * 32 + nr], acc);
        float val = fmaxf(acc, 0.f) * Wc2[nr];
        #pragma unroll
        for (int msk = 1; msk < 32; msk <<= 1) val += __shfl_xor(val, msk);
        if (nr == 0) out[b * 4 + g] = val + bc2[0];
    }
}

// ---------------------------------------------------------------------------
// f32 fallback — used only if ws too small or B % 4 != 0
// ---------------------------------------------------------------------------
__global__ __launch_bounds__(256, 4) void gat_fused_f32(
    const float* __restrict__ x_in, const float* __restrict__ W1,
    const float* __restrict__ a_src1, const float* __restrict__ a_dst1,
    const float* __restrict__ b1, const float* __restrict__ W2,
    const float* __restrict__ a_src2, const float* __restrict__ a_dst2,
    const float* __restrict__ b2, const float* __restrict__ Wc1,
    const float* __restrict__ bc1, const float* __restrict__ Wc2,
    const float* __restrict__ bc2, float* __restrict__ out)
{
    __shared__ union {
        float x_l[NN][FIN];
        struct { float h2[NN][C2]; float x3[NN][C2]; } s2;
    } u;
    __shared__ float h1s[NN][D1];
    __shared__ float x2s[NN][D1];
    __shared__ float alpha1[NN][NN][4];
    __shared__ float e_s1[NN][4], e_d1[NN][4];
    __shared__ float e_s2[NN], e_d2[NN];
    __shared__ float alpha2[NN][NN];
    __shared__ float gph[C2];
    __shared__ float hdn[32];

    const int b = blockIdx.x, t = threadIdx.x;
    const float* xb = x_in + (size_t)b * (NN * FIN);
    for (int i = t; i < NN * FIN; i += 256) (&u.x_l[0][0])[i] = xb[i];
    __syncthreads();
    {
        const int o0 = (t & 127) * 2, n0 = (t >> 7) * 6;
        float acc[6][2];
        #pragma unroll
        for (int i = 0; i < 6; ++i) { acc[i][0] = 0.f; acc[i][1] = 0.f; }
        for (int f = 0; f < FIN; f += 4) {
            float4 xv[6];
            #pragma unroll
            for (int i = 0; i < 6; ++i) xv[i] = *(const float4*)&u.x_l[n0 + i][f];
            #pragma unroll
            for (int k = 0; k < 4; ++k) {
                const float2 wv = *(const float2*)&W1[(f + k) * D1 + o0];
                #pragma unroll
                for (int i = 0; i < 6; ++i) {
                    const float xs = ((const float*)&xv[i])[k];
                    acc[i][0] = fmaf(xs, wv.x, acc[i][0]);
                    acc[i][1] = fmaf(xs, wv.y, acc[i][1]);
                }
            }
        }
        #pragma unroll
        for (int i = 0; i < 6; ++i) { h1s[n0+i][o0] = acc[i][0]; h1s[n0+i][o0+1] = acc[i][1]; }
    }
    __syncthreads();
    if (t < NN * 4) {
        const int n = t >> 2, h = t & 3;
        float es = 0.f, ed = 0.f;
        for (int c = 0; c < 64; ++c) {
            const float v = h1s[n][h * 64 + c];
            es = fmaf(v, a_src1[h * 64 + c], es);
            ed = fmaf(v, a_dst1[h * 64 + c], ed);
        }
        e_s1[n][h] = es; e_d1[n][h] = ed;
    }
    __syncthreads();
    if (t < NN * 4) {
        const int i = t >> 2, h = t & 3;
        const float edi = e_d1[i][h];
        float lv[NN]; float m = -1e30f;
        #pragma unroll
        for (int j = 0; j < NN; ++j) {
            float v = edi + e_s1[j][h]; v = v > 0.f ? v : SLOPE * v;
            lv[j] = v; m = fmaxf(m, v);
        }
        float s = 0.f;
        #pragma unroll
        for (int j = 0; j < NN; ++j) { lv[j] = __expf(lv[j] - m); s += lv[j]; }
        const float inv = 1.f / s;
        #pragma unroll
        for (int j = 0; j < NN; ++j) alpha1[i][j][h] = lv[j] * inv;
    }
    __syncthreads();
    {
        const int o = t, h = o >> 6;
        const float bo = b1[o];
        float v[NN];
        #pragma unroll
        for (int j = 0; j < NN; ++j) v[j] = h1s[j][o];
        #pragma unroll
        for (int i = 0; i < NN; ++i) {
            float acc = 0.f;
            #pragma unroll
            for (int j = 0; j < NN; ++j) acc = fmaf(alpha1[i][j][h], v[j], acc);
            x2s[i][o] = elu1(acc + bo);
        }
    }
    __syncthreads();
    {
        const int c = t & 63, n0 = (t >> 6) * 3;
        float acc[3] = {0.f, 0.f, 0.f};
        for (int f = 0; f < D1; f += 4) {
            float4 xv[3];
            #pragma unroll
            for (int i = 0; i < 3; ++i) xv[i] = *(const float4*)&x2s[n0 + i][f];
            #pragma unroll
            for (int k = 0; k < 4; ++k) {
                const float wv = W2[(f + k) * C2 + c];
                #pragma unroll
                for (int i = 0; i < 3; ++i) acc[i] = fmaf(((const float*)&xv[i])[k], wv, acc[i]);
            }
        }
        #pragma unroll
        for (int i = 0; i < 3; ++i) u.s2.h2[n0 + i][c] = acc[i];
    }
    __syncthreads();
    if (t < NN) {
        float es = 0.f, ed = 0.f;
        for (int c = 0; c < 64; c += 4) {
            const float4 v  = *(const float4*)&u.s2.h2[t][c];
            const float4 as = *(const float4*)&a_src2[c];
            const float4 ad = *(const float4*)&a_dst2[c];
            es += v.x*as.x + v.y*as.y + v.z*as.z + v.w*as.w;
            ed += v.x*ad.x + v.y*ad.y + v.z*ad.z + v.w*ad.w;
        }
        e_s2[t] = es; e_d2[t] = ed;
    }
    __syncthreads();
    if (t < NN) {
        const float edi = e_d2[t];
        float lv[NN]; float m = -1e30f;
        #pragma unroll
        for (int j = 0; j < NN; ++j) {
            float v = edi + e_s2[j]; v = v > 0.f ? v : SLOPE * v;
            lv[j] = v; m = fmaxf(m, v);
        }
        float s = 0.f;
        #pragma unroll
        for (int j = 0; j < NN; ++j) { lv[j] = __expf(lv[j] - m); s += lv[j]; }
        const float inv = 1.f / s;
        #pragma unroll
        for (int j = 0; j < NN; ++j) alpha2[t][j] = lv[j] * inv;
    }
    __syncthreads();
    {
        const int c = t & 63, i0 = (t >> 6) * 3;
        float v[NN];
        #pragma unroll
        for (int j = 0; j < NN; ++j) v[j] = u.s2.h2[j][c];
        const float bc = b2[c];
        #pragma unroll
        for (int ii = 0; ii < 3; ++ii) {
            const int i = i0 + ii;
            float acc = 0.f;
            #pragma unroll
            for (int j = 0; j < NN; ++j) acc = fmaf(alpha2[i][j], v[j], acc);
            u.s2.x3[i][c] = elu1(acc + bc);
        }
    }
    __syncthreads();
    if (t < C2) {
        float s = 0.f;
        #pragma unroll
        for (int i = 0; i < NN; ++i) s += u.s2.x3[i][t];
        gph[t] = s * (1.0f / NN);
    }
    __syncthreads();
    if (t < 32) {
        float acc = bc1[t];
        for (int c = 0; c < C2; ++c) acc = fmaf(gph[c], Wc1[c * 32 + t], acc);
        hdn[t] = fmaxf(acc, 0.f);
    }
    __syncthreads();
    if (t == 0) {
        float acc = bc2[0];
        #pragma unroll
        for (int k = 0; k < 32; ++k) acc = fmaf(hdn[k], Wc2[k], acc);
        out[b] = acc;
    }
}

extern "C" void kernel_launch(void* const* d_in, const int* in_sizes, int n_in,
                              void* d_out, int out_size, void* d_ws, size_t ws_size,
                              hipStream_t stream) {
    const float* x   = (const float*)d_in[0];
    const float* W1  = (const float*)d_in[1];
    const float* as1 = (const float*)d_in[2];
    const float* ad1 = (const float*)d_in[3];
    const float* b1  = (const float*)d_in[4];
    const float* W2  = (const float*)d_in[5];
    const float* as2 = (const float*)d_in[6];
    const float* ad2 = (const float*)d_in[7];
    const float* b2  = (const float*)d_in[8];
    const float* Wc1 = (const float*)d_in[9];
    const float* bc1 = (const float*)d_in[10];
    const float* Wc2 = (const float*)d_in[11];
    const float* bc2 = (const float*)d_in[12];
    float* out = (float*)d_out;

    const int B = in_sizes[0] / (NN * FIN);

    if (ws_size >= 110592 && (B % 4) == 0) {
        unsigned short* wsB1 = (unsigned short*)d_ws;
        unsigned short* wsB2 = wsB1 + 34816;
        prep_weights<<<216, 256, 0, stream>>>(W1, as1, ad1, W2, as2, ad2, wsB1, wsB2);
        gat_mfma2<<<B / 4, 256, 0, stream>>>(x, wsB1, wsB2, b1, b2, Wc1, bc1, Wc2, bc2, out);
    } else {
        gat_fused_f32<<<B, 256, 0, stream>>>(x, W1, as1, ad1, b1, W2, as2, ad2, b2,
                                             Wc1, bc1, Wc2, bc2, out);
    }
}

// Round 6
// 169.231 us; speedup vs baseline: 5.7384x; 1.3649x over previous
//
#include <hip/hip_runtime.h>
#include <math.h>

typedef __attribute__((ext_vector_type(8))) short bf16x8;
typedef __attribute__((ext_vector_type(4))) float f32x4;

namespace {
constexpr int NN  = 12;
constexpr int FIN = 128;
constexpr int D1  = 256;
constexpr int C2  = 64;
constexpr float SLOPE = 0.2f;

__device__ __forceinline__ unsigned short f2bf(float f) {
    unsigned u = __builtin_bit_cast(unsigned, f);
    u += 0x7FFFu + ((u >> 16) & 1u);     // RNE
    return (unsigned short)(u >> 16);
}
// ELU via hardware v_exp_f32: exact enough (|err| ~1e-7) and ~5x cheaper than libm expm1f.
__device__ __forceinline__ float elu1(float x) { return x > 0.f ? x : __expf(x) - 1.f; }
__device__ __forceinline__ float lrelu(float x) { return x > 0.f ? x : SLOPE * x; }
}

// ---------------------------------------------------------------------------
// Pack B-operands into bf16 MFMA fragment layout, with attention-vector
// columns folded in as extra N-tiles (e-tile):
//   B1: [128 K][16 tiles of W1-cols + 1 e-tile]  -> idx ((kt*17+nt)*64+l)*8+i
//   B2: [256 K][4 tiles of W2-cols + 1 e-tile]   -> idx ((kt*5+nt)*64+l)*8+i
// fragment: lane l elem i <- B[k = kt*32+(l>>4)*8+i][c = nt*16+(l&15)]
// ---------------------------------------------------------------------------
__global__ void prep_weights(const float* __restrict__ W1, const float* __restrict__ as1,
                             const float* __restrict__ ad1,
                             const float* __restrict__ W2, const float* __restrict__ as2,
                             const float* __restrict__ ad2,
                             unsigned short* __restrict__ wsB1, unsigned short* __restrict__ wsB2) {
    int t = blockIdx.x * 256 + threadIdx.x;
    if (t < 34816) {
        int i = t & 7, l = (t >> 3) & 63, kn = t >> 9;    // kn 0..67
        int kt = kn / 17, nt = kn % 17;
        int k = kt * 32 + (l >> 4) * 8 + i;
        float v = 0.f;
        if (nt < 16) {
            v = W1[k * 256 + nt * 16 + (l & 15)];
        } else {
            int cc = l & 15;
            if (cc < 4)      for (int c = 0; c < 64; ++c) v += W1[k * 256 + cc * 64 + c] * as1[cc * 64 + c];
            else if (cc < 8) for (int c = 0; c < 64; ++c) v += W1[k * 256 + (cc - 4) * 64 + c] * ad1[(cc - 4) * 64 + c];
        }
        wsB1[t] = f2bf(v);
    } else if (t < 55296) {
        int t2 = t - 34816;
        int i = t2 & 7, l = (t2 >> 3) & 63, kn = t2 >> 9; // kn 0..39
        int kt = kn / 5, nt = kn % 5;
        int k = kt * 32 + (l >> 4) * 8 + i;
        float v = 0.f;
        if (nt < 4) {
            v = W2[k * 64 + nt * 16 + (l & 15)];
        } else {
            int cc = l & 15;
            if (cc == 0)      for (int c = 0; c < 64; ++c) v += W2[k * 64 + c] * as2[c];
            else if (cc == 1) for (int c = 0; c < 64; ++c) v += W2[k * 64 + c] * ad2[c];
        }
        wsB2[t2] = f2bf(v);
    }
}

// ---------------------------------------------------------------------------
// Main fused kernel: 4 graphs (48 rows) per block, 256 threads (4 waves).
// R3-proven addressing throughout. Grafts vs R3: __expf ELU, packed f2bf
// alpha stores (proven byte-identical to R3's scalar stores).
// NOTE: inline-asm v_cvt_pk_bf16_f32 caused R4/R5 1e37 blow-ups — banned.
// ---------------------------------------------------------------------------
__global__ __launch_bounds__(256, 2) void gat_mfma5(
    const float* __restrict__ x_in,
    const unsigned short* __restrict__ wsB1,
    const unsigned short* __restrict__ wsB2,
    const float* __restrict__ b1, const float* __restrict__ b2,
    const float* __restrict__ Wc1, const float* __restrict__ bc1,
    const float* __restrict__ Wc2, const float* __restrict__ bc2,
    float* __restrict__ out)
{
    // R0: x bf16 [48][128] swz (12288)           | x3 f32 [48][68] (13056)
    // R1: h1T bf16 [256 col][64 row] swz (32768) | h2T [64][64] (8192) + alpha2 [48][64] @+8192 (6144)
    // R2: alpha1 bf16 [4 h][48 i][64 j] (24576)  | x2 bf16 [4 head][48][64] swz (same geometry)
    __shared__ __align__(16) unsigned char R0[13056];
    __shared__ __align__(16) unsigned char R1[32768];
    __shared__ __align__(16) unsigned char R2[24576];
    __shared__ float eS1[48][4], eD1[48][4];
    __shared__ float eS2[48], eD2[48];
    __shared__ float gpool[4][64];

    const int b = blockIdx.x, t = threadIdx.x;
    const int w = t >> 6, l = t & 63, l15 = l & 15, lq = l >> 4;

    // ---- P0: stage x (f32 -> bf16 LDS swizzled) + zero-fill padding regions
    {
        const float4* xs = (const float4*)(x_in + (size_t)b * (4 * NN * FIN));
        #pragma unroll
        for (int it = 0; it < 6; ++it) {
            int q = t + 256 * it;
            float4 v = xs[q];
            int e0 = q << 2, r = e0 >> 7, k = e0 & 127;
            int addr = ((r << 8) + (k << 1)) ^ ((r & 7) << 4);
            unsigned p0 = (unsigned)f2bf(v.x) | ((unsigned)f2bf(v.y) << 16);
            unsigned p1 = (unsigned)f2bf(v.z) | ((unsigned)f2bf(v.w) << 16);
            *(uint2*)(R0 + addr) = make_uint2(p0, p1);
        }
        #pragma unroll
        for (int it = 0; it < 6; ++it)                     // zero alpha1 (24576 B)
            *(uint4*)(R2 + ((it * 256 + t) << 4)) = make_uint4(0, 0, 0, 0);
        #pragma unroll
        for (int z = 0; z < 2; ++z) {                      // zero h1T rows 48..63
            int id = t + 256 * z;                          // 512 x 16B
            int col = id >> 1, bs = 6 + (id & 1);
            int addr = ((col << 7) + (bs << 4)) ^ ((col & 7) << 4);
            *(uint4*)(R1 + addr) = make_uint4(0, 0, 0, 0);
        }
    }
    __syncthreads();

    // ---- P1: GEMM1 (x @ [W1 | va1]) -> h1T bf16 + eS1/eD1 direct
    {
        const uint4* pb = (const uint4*)wsB1;
        bf16x8 Bf[4][4];
        #pragma unroll
        for (int ng = 0; ng < 4; ++ng)
            #pragma unroll
            for (int kt = 0; kt < 4; ++kt)
                Bf[ng][kt] = __builtin_bit_cast(bf16x8, pb[(kt * 17 + (w * 4 + ng)) * 64 + l]);
        bf16x8 Bfe[4];
        if (w == 0) {
            #pragma unroll
            for (int kt = 0; kt < 4; ++kt)
                Bfe[kt] = __builtin_bit_cast(bf16x8, pb[(kt * 17 + 16) * 64 + l]);
        }
        #pragma unroll
        for (int m = 0; m < 3; ++m) {
            int r = m * 16 + l15, abase = (r << 8) + (lq << 4), swz = (r & 7) << 4;
            bf16x8 Af[4];
            #pragma unroll
            for (int kt = 0; kt < 4; ++kt)
                Af[kt] = *(const bf16x8*)(R0 + ((abase + (kt << 6)) ^ swz));
            f32x4 acc[4];
            #pragma unroll
            for (int ng = 0; ng < 4; ++ng) acc[ng] = (f32x4){0.f, 0.f, 0.f, 0.f};
            #pragma unroll
            for (int ng = 0; ng < 4; ++ng)
                #pragma unroll
                for (int kt = 0; kt < 4; ++kt)
                    acc[ng] = __builtin_amdgcn_mfma_f32_16x16x32_bf16(Af[kt], Bf[ng][kt], acc[ng], 0, 0, 0);
            int row0 = m * 16 + lq * 4;
            #pragma unroll
            for (int ng = 0; ng < 4; ++ng) {               // packed b64 store (4 consecutive rows)
                int col = w * 64 + ng * 16 + l15;
                unsigned q0 = (unsigned)f2bf(acc[ng][0]) | ((unsigned)f2bf(acc[ng][1]) << 16);
                unsigned q1 = (unsigned)f2bf(acc[ng][2]) | ((unsigned)f2bf(acc[ng][3]) << 16);
                int addr = ((col << 7) + (row0 << 1)) ^ ((col & 7) << 4);
                *(uint2*)(R1 + addr) = make_uint2(q0, q1);
            }
            if (w == 0) {
                f32x4 acce = (f32x4){0.f, 0.f, 0.f, 0.f};
                #pragma unroll
                for (int kt = 0; kt < 4; ++kt)
                    acce = __builtin_amdgcn_mfma_f32_16x16x32_bf16(Af[kt], Bfe[kt], acce, 0, 0, 0);
                if (l15 < 8) {
                    #pragma unroll
                    for (int reg = 0; reg < 4; ++reg) {
                        int row = row0 + reg;
                        if (l15 < 4) eS1[row][l15] = acce[reg];
                        else         eD1[row][l15 - 4] = acce[reg];
                    }
                }
            }
        }
    }
    __syncthreads();

    // ---- P2: softmax1 -> alpha1[h][i][j] bf16 (A-fragment layout, blockdiag),
    //      packed uint2 writes (byte-identical to R3's scalar writes)
    if (t < 192) {
        int g = t / 48, rem = t % 48, i = rem >> 2, h = rem & 3;
        int rowi = g * 12 + i;
        float edi = eD1[rowi][h];
        float lv[12]; float mx = -1e30f;
        #pragma unroll
        for (int j = 0; j < 12; ++j) {
            float v = lrelu(edi + eS1[g * 12 + j][h]);
            lv[j] = v; mx = fmaxf(mx, v);
        }
        float s = 0.f;
        #pragma unroll
        for (int j = 0; j < 12; ++j) { lv[j] = __expf(lv[j] - mx); s += lv[j]; }
        float inv = 1.f / s;
        unsigned char* base = R2 + h * 6144;
        int rb = rowi << 7, swz = (rowi & 7) << 4, ob = g * 24;
        #pragma unroll
        for (int p = 0; p < 3; ++p) {
            unsigned q0 = (unsigned)f2bf(lv[4*p]   * inv) | ((unsigned)f2bf(lv[4*p+1] * inv) << 16);
            unsigned q1 = (unsigned)f2bf(lv[4*p+2] * inv) | ((unsigned)f2bf(lv[4*p+3] * inv) << 16);
            int addr = (rb + ob + p * 8) ^ swz;
            *(uint2*)(base + addr) = make_uint2(q0, q1);
        }
    }
    __syncthreads();

    // ---- P3: aggregation1 via MFMA (alpha1_h @ h1_h) + bias + ELU -> x2 (overlays alpha1)
    {
        bf16x8 Bh[2][4];
        #pragma unroll
        for (int kt = 0; kt < 2; ++kt)
            #pragma unroll
            for (int nt = 0; nt < 4; ++nt) {
                int col = w * 64 + nt * 16 + l15;
                int addr = ((col << 7) + (kt << 6) + (lq << 4)) ^ ((col & 7) << 4);
                Bh[kt][nt] = *(const bf16x8*)(R1 + addr);
            }
        float b1v[4];
        #pragma unroll
        for (int nt = 0; nt < 4; ++nt) b1v[nt] = b1[w * 64 + nt * 16 + l15];
        unsigned char* aab = R2 + w * 6144;   // wave w: alpha of head w, then x2 of head w
        #pragma unroll
        for (int m = 0; m < 3; ++m) {
            int r = m * 16 + l15, swz = (r & 7) << 4;
            bf16x8 Aa[2];
            #pragma unroll
            for (int kt = 0; kt < 2; ++kt)
                Aa[kt] = *(const bf16x8*)(aab + (((r << 7) + (kt << 6) + (lq << 4)) ^ swz));
            #pragma unroll
            for (int nt = 0; nt < 4; ++nt) {
                f32x4 acc = (f32x4){0.f, 0.f, 0.f, 0.f};
                #pragma unroll
                for (int kt = 0; kt < 2; ++kt)
                    acc = __builtin_amdgcn_mfma_f32_16x16x32_bf16(Aa[kt], Bh[kt][nt], acc, 0, 0, 0);
                #pragma unroll
                for (int reg = 0; reg < 4; ++reg) {
                    int row = m * 16 + lq * 4 + reg;
                    float val = elu1(acc[reg] + b1v[nt]);
                    int addr = ((row << 7) + ((nt * 16 + l15) << 1)) ^ ((row & 7) << 4);
                    *(unsigned short*)(aab + addr) = f2bf(val);
                }
            }
        }
    }
    __syncthreads();

    // ---- P4: GEMM2 (x2 @ [W2 | va2]) -> h2T bf16 + eS2/eD2; zero pads
    {
        if (t < 128) {                                     // zero h2T rows 48..63
            int col = t >> 1, bs = 6 + (t & 1);
            int addr = ((col << 7) + (bs << 4)) ^ ((col & 7) << 4);
            *(uint4*)(R1 + addr) = make_uint4(0, 0, 0, 0);
        }
        if (t < 192) {                                     // zero alpha2 (6144 B)
            *(uint4*)(R1 + 8192 + (t << 4)) = make_uint4(0, 0, 0, 0);
            *(uint4*)(R1 + 8192 + ((t + 192) << 4)) = make_uint4(0, 0, 0, 0);
        }
        const uint4* pb2 = (const uint4*)wsB2;
        bf16x8 Bg[8], Be2[8];
        #pragma unroll
        for (int kt = 0; kt < 8; ++kt)
            Bg[kt] = __builtin_bit_cast(bf16x8, pb2[(kt * 5 + w) * 64 + l]);
        if (w == 0) {
            #pragma unroll
            for (int kt = 0; kt < 8; ++kt)
                Be2[kt] = __builtin_bit_cast(bf16x8, pb2[(kt * 5 + 4) * 64 + l]);
        }
        #pragma unroll
        for (int m = 0; m < 3; ++m) {
            int r = m * 16 + l15, swz = (r & 7) << 4;
            f32x4 acc = (f32x4){0.f, 0.f, 0.f, 0.f}, acce = (f32x4){0.f, 0.f, 0.f, 0.f};
            #pragma unroll
            for (int kt = 0; kt < 8; ++kt) {
                int addr = (kt >> 1) * 6144 + (((r << 7) + ((kt & 1) << 6) + (lq << 4)) ^ swz);
                bf16x8 Ax = *(const bf16x8*)(R2 + addr);
                acc = __builtin_amdgcn_mfma_f32_16x16x32_bf16(Ax, Bg[kt], acc, 0, 0, 0);
                if (w == 0) acce = __builtin_amdgcn_mfma_f32_16x16x32_bf16(Ax, Be2[kt], acce, 0, 0, 0);
            }
            int col = w * 16 + l15, row0 = m * 16 + lq * 4;
            unsigned q0 = (unsigned)f2bf(acc[0]) | ((unsigned)f2bf(acc[1]) << 16);
            unsigned q1 = (unsigned)f2bf(acc[2]) | ((unsigned)f2bf(acc[3]) << 16);
            int addr = ((col << 7) + (row0 << 1)) ^ ((col & 7) << 4);
            *(uint2*)(R1 + addr) = make_uint2(q0, q1);
            if (w == 0 && l15 < 2) {
                #pragma unroll
                for (int reg = 0; reg < 4; ++reg) {
                    int row = row0 + reg;
                    if (l15 == 0) eS2[row] = acce[reg];
                    else          eD2[row] = acce[reg];
                }
            }
        }
    }
    __syncthreads();

    // ---- P5: softmax2 -> alpha2[i][j] bf16, packed uint2 writes
    if (t < 48) {
        int g = t / 12;
        float edi = eD2[t];
        float lv[12]; float mx = -1e30f;
        #pragma unroll
        for (int j = 0; j < 12; ++j) {
            float v = lrelu(edi + eS2[g * 12 + j]);
            lv[j] = v; mx = fmaxf(mx, v);
        }
        float s = 0.f;
        #pragma unroll
        for (int j = 0; j < 12; ++j) { lv[j] = __expf(lv[j] - mx); s += lv[j]; }
        float inv = 1.f / s;
        int rb = t << 7, swz = (t & 7) << 4, ob = g * 24;
        #pragma unroll
        for (int p = 0; p < 3; ++p) {
            unsigned q0 = (unsigned)f2bf(lv[4*p]   * inv) | ((unsigned)f2bf(lv[4*p+1] * inv) << 16);
            unsigned q1 = (unsigned)f2bf(lv[4*p+2] * inv) | ((unsigned)f2bf(lv[4*p+3] * inv) << 16);
            int addr = 8192 + ((rb + ob + p * 8) ^ swz);
            *(uint2*)(R1 + addr) = make_uint2(q0, q1);
        }
    }
    __syncthreads();

    // ---- P6: aggregation2 via MFMA + bias + ELU -> x3 f32 (overlays R0)
    {
        bf16x8 Bh2[2];
        int col = w * 16 + l15;
        #pragma unroll
        for (int kt = 0; kt < 2; ++kt) {
            int addr = ((col << 7) + (kt << 6) + (lq << 4)) ^ ((col & 7) << 4);
            Bh2[kt] = *(const bf16x8*)(R1 + addr);
        }
        float b2v = b2[col];
        #pragma unroll
        for (int m = 0; m < 3; ++m) {
            int r = m * 16 + l15, swz = (r & 7) << 4;
            f32x4 acc = (f32x4){0.f, 0.f, 0.f, 0.f};
            #pragma unroll
            for (int kt = 0; kt < 2; ++kt) {
                bf16x8 Aa = *(const bf16x8*)(R1 + 8192 + (((r << 7) + (kt << 6) + (lq << 4)) ^ swz));
                acc = __builtin_amdgcn_mfma_f32_16x16x32_bf16(Aa, Bh2[kt], acc, 0, 0, 0);
            }
            #pragma unroll
            for (int reg = 0; reg < 4; ++reg) {
                int row = m * 16 + lq * 4 + reg;
                *(float*)(R0 + row * 272 + (col << 2)) = elu1(acc[reg] + b2v);
            }
        }
    }
    __syncthreads();

    // ---- pool
    {
        int o = t & 63, g = t >> 6;
        float s = 0.f;
        #pragma unroll
        for (int j = 0; j < 12; ++j)
            s += *(const float*)(R0 + (g * 12 + j) * 272 + (o << 2));
        gpool[g][o] = s * (1.0f / 12.0f);
    }
    __syncthreads();

    // ---- classifier 64 -> 32 (relu) -> 1
    if (t < 128) {
        int g = t >> 5, nr = t & 31;
        float acc = bc1[nr];
        #pragma unroll
        for (int cc = 0; cc < 64; ++cc)
            acc = fmaf(gpool[g][cc], Wc1[cc * 32 + nr], acc);
        float val = fmaxf(acc, 0.f) * Wc2[nr];
        #pragma unroll
        for (int msk = 1; msk < 32; msk <<= 1) val += __shfl_xor(val, msk);
        if (nr == 0) out[b * 4 + g] = val + bc2[0];
    }
}

// ---------------------------------------------------------------------------
// f32 fallback — used only if ws too small or B % 4 != 0
// ---------------------------------------------------------------------------
__global__ __launch_bounds__(256, 4) void gat_fused_f32(
    const float* __restrict__ x_in, const float* __restrict__ W1,
    const float* __restrict__ a_src1, const float* __restrict__ a_dst1,
    const float* __restrict__ b1, const float* __restrict__ W2,
    const float* __restrict__ a_src2, const float* __restrict__ a_dst2,
    const float* __restrict__ b2, const float* __restrict__ Wc1,
    const float* __restrict__ bc1, const float* __restrict__ Wc2,
    const float* __restrict__ bc2, float* __restrict__ out)
{
    __shared__ union {
        float x_l[NN][FIN];
        struct { float h2[NN][C2]; float x3[NN][C2]; } s2;
    } u;
    __shared__ float h1s[NN][D1];
    __shared__ float x2s[NN][D1];
    __shared__ float alpha1[NN][NN][4];
    __shared__ float e_s1[NN][4], e_d1[NN][4];
    __shared__ float e_s2[NN], e_d2[NN];
    __shared__ float alpha2[NN][NN];
    __shared__ float gph[C2];
    __shared__ float hdn[32];

    const int b = blockIdx.x, t = threadIdx.x;
    const float* xb = x_in + (size_t)b * (NN * FIN);
    for (int i = t; i < NN * FIN; i += 256) (&u.x_l[0][0])[i] = xb[i];
    __syncthreads();
    {
        const int o0 = (t & 127) * 2, n0 = (t >> 7) * 6;
        float acc[6][2];
        #pragma unroll
        for (int i = 0; i < 6; ++i) { acc[i][0] = 0.f; acc[i][1] = 0.f; }
        for (int f = 0; f < FIN; f += 4) {
            float4 xv[6];
            #pragma unroll
            for (int i = 0; i < 6; ++i) xv[i] = *(const float4*)&u.x_l[n0 + i][f];
            #pragma unroll
            for (int k = 0; k < 4; ++k) {
                const float2 wv = *(const float2*)&W1[(f + k) * D1 + o0];
                #pragma unroll
                for (int i = 0; i < 6; ++i) {
                    const float xs = ((const float*)&xv[i])[k];
                    acc[i][0] = fmaf(xs, wv.x, acc[i][0]);
                    acc[i][1] = fmaf(xs, wv.y, acc[i][1]);
                }
            }
        }
        #pragma unroll
        for (int i = 0; i < 6; ++i) { h1s[n0+i][o0] = acc[i][0]; h1s[n0+i][o0+1] = acc[i][1]; }
    }
    __syncthreads();
    if (t < NN * 4) {
        const int n = t >> 2, h = t & 3;
        float es = 0.f, ed = 0.f;
        for (int c = 0; c < 64; ++c) {
            const float v = h1s[n][h * 64 + c];
            es = fmaf(v, a_src1[h * 64 + c], es);
            ed = fmaf(v, a_dst1[h * 64 + c], ed);
        }
        e_s1[n][h] = es; e_d1[n][h] = ed;
    }
    __syncthreads();
    if (t < NN * 4) {
        const int i = t >> 2, h = t & 3;
        const float edi = e_d1[i][h];
        float lv[NN]; float m = -1e30f;
        #pragma unroll
        for (int j = 0; j < NN; ++j) {
            float v = edi + e_s1[j][h]; v = v > 0.f ? v : SLOPE * v;
            lv[j] = v; m = fmaxf(m, v);
        }
        float s = 0.f;
        #pragma unroll
        for (int j = 0; j < NN; ++j) { lv[j] = __expf(lv[j] - m); s += lv[j]; }
        const float inv = 1.f / s;
        #pragma unroll
        for (int j = 0; j < NN; ++j) alpha1[i][j][h] = lv[j] * inv;
    }
    __syncthreads();
    {
        const int o = t, h = o >> 6;
        const float bo = b1[o];
        float v[NN];
        #pragma unroll
        for (int j = 0; j < NN; ++j) v[j] = h1s[j][o];
        #pragma unroll
        for (int i = 0; i < NN; ++i) {
            float acc = 0.f;
            #pragma unroll
            for (int j = 0; j < NN; ++j) acc = fmaf(alpha1[i][j][h], v[j], acc);
            x2s[i][o] = acc + bo > 0.f ? acc + bo : expm1f(acc + bo);
        }
    }
    __syncthreads();
    {
        const int c = t & 63, n0 = (t >> 6) * 3;
        float acc[3] = {0.f, 0.f, 0.f};
        for (int f = 0; f < D1; f += 4) {
            float4 xv[3];
            #pragma unroll
            for (int i = 0; i < 3; ++i) xv[i] = *(const float4*)&x2s[n0 + i][f];
            #pragma unroll
            for (int k = 0; k < 4; ++k) {
                const float wv = W2[(f + k) * C2 + c];
                #pragma unroll
                for (int i = 0; i < 3; ++i) acc[i] = fmaf(((const float*)&xv[i])[k], wv, acc[i]);
            }
        }
        #pragma unroll
        for (int i = 0; i < 3; ++i) u.s2.h2[n0 + i][c] = acc[i];
    }
    __syncthreads();
    if (t < NN) {
        float es = 0.f, ed = 0.f;
        for (int c = 0; c < 64; c += 4) {
            const float4 v  = *(const float4*)&u.s2.h2[t][c];
            const float4 as = *(const float4*)&a_src2[c];
            const float4 ad = *(const float4*)&a_dst2[c];
            es += v.x*as.x + v.y*as.y + v.z*as.z + v.w*as.w;
            ed += v.x*ad.x + v.y*ad.y + v.z*ad.z + v.w*ad.w;
        }
        e_s2[t] = es; e_d2[t] = ed;
    }
    __syncthreads();
    if (t < NN) {
        const float edi = e_d2[t];
        float lv[NN]; float m = -1e30f;
        #pragma unroll
        for (int j = 0; j < NN; ++j) {
            float v = edi + e_s2[j]; v = v > 0.f ? v : SLOPE * v;
            lv[j] = v; m = fmaxf(m, v);
        }
        float s = 0.f;
        #pragma unroll
        for (int j = 0; j < NN; ++j) { lv[j] = __expf(lv[j] - m); s += lv[j]; }
        const float inv = 1.f / s;
        #pragma unroll
        for (int j = 0; j < NN; ++j) alpha2[t][j] = lv[j] * inv;
    }
    __syncthreads();
    {
        const int c = t & 63, i0 = (t >> 6) * 3;
        float v[NN];
        #pragma unroll
        for (int j = 0; j < NN; ++j) v[j] = u.s2.h2[j][c];
        const float bc = b2[c];
        #pragma unroll
        for (int ii = 0; ii < 3; ++ii) {
            const int i = i0 + ii;
            float acc = 0.f;
            #pragma unroll
            for (int j = 0; j < NN; ++j) acc = fmaf(alpha2[i][j], v[j], acc);
            u.s2.x3[i][c] = acc + bc > 0.f ? acc + bc : expm1f(acc + bc);
        }
    }
    __syncthreads();
    if (t < C2) {
        float s = 0.f;
        #pragma unroll
        for (int i = 0; i < NN; ++i) s += u.s2.x3[i][t];
        gph[t] = s * (1.0f / NN);
    }
    __syncthreads();
    if (t < 32) {
        float acc = bc1[t];
        for (int c = 0; c < C2; ++c) acc = fmaf(gph[c], Wc1[c * 32 + t], acc);
        hdn[t] = fmaxf(acc, 0.f);
    }
    __syncthreads();
    if (t == 0) {
        float acc = bc2[0];
        #pragma unroll
        for (int k = 0; k < 32; ++k) acc = fmaf(hdn[k], Wc2[k], acc);
        out[b] = acc;
    }
}

extern "C" void kernel_launch(void* const* d_in, const int* in_sizes, int n_in,
                              void* d_out, int out_size, void* d_ws, size_t ws_size,
                              hipStream_t stream) {
    const float* x   = (const float*)d_in[0];
    const float* W1  = (const float*)d_in[1];
    const float* as1 = (const float*)d_in[2];
    const float* ad1 = (const float*)d_in[3];
    const float* b1  = (const float*)d_in[4];
    const float* W2  = (const float*)d_in[5];
    const float* as2 = (const float*)d_in[6];
    const float* ad2 = (const float*)d_in[7];
    const float* b2  = (const float*)d_in[8];
    const float* Wc1 = (const float*)d_in[9];
    const float* bc1 = (const float*)d_in[10];
    const float* Wc2 = (const float*)d_in[11];
    const float* bc2 = (const float*)d_in[12];
    float* out = (float*)d_out;

    const int B = in_sizes[0] / (NN * FIN);

    if (ws_size >= 110592 && (B % 4) == 0) {
        unsigned short* wsB1 = (unsigned short*)d_ws;
        unsigned short* wsB2 = wsB1 + 34816;
        prep_weights<<<216, 256, 0, stream>>>(W1, as1, ad1, W2, as2, ad2, wsB1, wsB2);
        gat_mfma5<<<B / 4, 256, 0, stream>>>(x, wsB1, wsB2, b1, b2, Wc1, bc1, Wc2, bc2, out);
    } else {
        gat_fused_f32<<<B, 256, 0, stream>>>(x, W1, as1, ad1, b1, W2, as2, ad2, b2,
                                             Wc1, bc1, Wc2, bc2, out);
    }
}

// Round 7
// 155.819 us; speedup vs baseline: 6.2323x; 1.0861x over previous
//
#include <hip/hip_runtime.h>
#include <math.h>

typedef __attribute__((ext_vector_type(8))) short bf16x8;
typedef __attribute__((ext_vector_type(4))) float f32x4;

namespace {
constexpr int NN  = 12;
constexpr int FIN = 128;
constexpr int D1  = 256;
constexpr int C2  = 64;
constexpr float SLOPE = 0.2f;

__device__ __forceinline__ unsigned short f2bf(float f) {
    unsigned u = __builtin_bit_cast(unsigned, f);
    u += 0x7FFFu + ((u >> 16) & 1u);     // RNE
    return (unsigned short)(u >> 16);
}
// ELU via hardware v_exp_f32 (~1e-7 err, ~5x cheaper than libm expm1f).
__device__ __forceinline__ float elu1(float x) { return x > 0.f ? x : __expf(x) - 1.f; }
__device__ __forceinline__ float lrelu(float x) { return x > 0.f ? x : SLOPE * x; }
}

// ---------------------------------------------------------------------------
// Pack B-operands into bf16 MFMA fragment layout, e-tiles folded in (R3).
// ---------------------------------------------------------------------------
__global__ void prep_weights(const float* __restrict__ W1, const float* __restrict__ as1,
                             const float* __restrict__ ad1,
                             const float* __restrict__ W2, const float* __restrict__ as2,
                             const float* __restrict__ ad2,
                             unsigned short* __restrict__ wsB1, unsigned short* __restrict__ wsB2) {
    int t = blockIdx.x * 256 + threadIdx.x;
    if (t < 34816) {
        int i = t & 7, l = (t >> 3) & 63, kn = t >> 9;    // kn 0..67
        int kt = kn / 17, nt = kn % 17;
        int k = kt * 32 + (l >> 4) * 8 + i;
        float v = 0.f;
        if (nt < 16) {
            v = W1[k * 256 + nt * 16 + (l & 15)];
        } else {
            int cc = l & 15;
            if (cc < 4)      for (int c = 0; c < 64; ++c) v += W1[k * 256 + cc * 64 + c] * as1[cc * 64 + c];
            else if (cc < 8) for (int c = 0; c < 64; ++c) v += W1[k * 256 + (cc - 4) * 64 + c] * ad1[(cc - 4) * 64 + c];
        }
        wsB1[t] = f2bf(v);
    } else if (t < 55296) {
        int t2 = t - 34816;
        int i = t2 & 7, l = (t2 >> 3) & 63, kn = t2 >> 9; // kn 0..39
        int kt = kn / 5, nt = kn % 5;
        int k = kt * 32 + (l >> 4) * 8 + i;
        float v = 0.f;
        if (nt < 4) {
            v = W2[k * 64 + nt * 16 + (l & 15)];
        } else {
            int cc = l & 15;
            if (cc == 0)      for (int c = 0; c < 64; ++c) v += W2[k * 64 + c] * as2[c];
            else if (cc == 1) for (int c = 0; c < 64; ++c) v += W2[k * 64 + c] * ad2[c];
        }
        wsB2[t2] = f2bf(v);
    }
}

// ---------------------------------------------------------------------------
// Main fused kernel: 4 graphs (48 rows), 512 threads (8 waves) per block.
// Identical address math to R6 (hardware-proven); wave pairs split the
// N-dimension of each phase to double occupancy (2 blk/CU x 8 waves = 50%).
// ---------------------------------------------------------------------------
__global__ __launch_bounds__(512, 4) void gat_mfma6(
    const float* __restrict__ x_in,
    const unsigned short* __restrict__ wsB1,
    const unsigned short* __restrict__ wsB2,
    const float* __restrict__ b1, const float* __restrict__ b2,
    const float* __restrict__ Wc1, const float* __restrict__ bc1,
    const float* __restrict__ Wc2, const float* __restrict__ bc2,
    float* __restrict__ out)
{
    // R0: x bf16 [48][128] swz (12288)           | x3 f32 [48][68] (13056)
    // R1: h1T bf16 [256 col][64 row] swz (32768) | h2T [64][64] (8192) + alpha2 [48][64] @+8192 (6144)
    // R2: alpha1 bf16 [4 h][48 i][64 j] (24576)  | x2 bf16 [4 head][48][64] swz (same geometry)
    __shared__ __align__(16) unsigned char R0[13056];
    __shared__ __align__(16) unsigned char R1[32768];
    __shared__ __align__(16) unsigned char R2[24576];
    __shared__ float eS1[48][4], eD1[48][4];
    __shared__ float eS2[48], eD2[48];
    __shared__ float gpool[4][64];

    const int b = blockIdx.x, t = threadIdx.x;
    const int w = t >> 6, l = t & 63, l15 = l & 15, lq = l >> 4;

    // ---- P0: stage x (f32 -> bf16 LDS swizzled) + zero-fill padding regions
    {
        const float4* xs = (const float4*)(x_in + (size_t)b * (4 * NN * FIN));
        #pragma unroll
        for (int it = 0; it < 3; ++it) {
            int q = t + 512 * it;                          // 1536 float4
            float4 v = xs[q];
            int e0 = q << 2, r = e0 >> 7, k = e0 & 127;
            int addr = ((r << 8) + (k << 1)) ^ ((r & 7) << 4);
            unsigned p0 = (unsigned)f2bf(v.x) | ((unsigned)f2bf(v.y) << 16);
            unsigned p1 = (unsigned)f2bf(v.z) | ((unsigned)f2bf(v.w) << 16);
            *(uint2*)(R0 + addr) = make_uint2(p0, p1);
        }
        #pragma unroll
        for (int it = 0; it < 3; ++it)                     // zero alpha1 (24576 B)
            *(uint4*)(R2 + ((it * 512 + t) << 4)) = make_uint4(0, 0, 0, 0);
        {                                                  // zero h1T rows 48..63 (512 x 16B)
            int col = t >> 1, bs = 6 + (t & 1);
            int addr = ((col << 7) + (bs << 4)) ^ ((col & 7) << 4);
            *(uint4*)(R1 + addr) = make_uint4(0, 0, 0, 0);
        }
    }
    __syncthreads();

    // ---- P1: GEMM1 (x @ [W1 | va1]) -> h1T bf16 + eS1/eD1 direct
    //      wave pair (2h, 2h+1) splits head h's 4 n-tiles into 2+2
    {
        const uint4* pb = (const uint4*)wsB1;
        const int h = w >> 1, half = w & 1;
        bf16x8 Bf[2][4];
        #pragma unroll
        for (int ngl = 0; ngl < 2; ++ngl)
            #pragma unroll
            for (int kt = 0; kt < 4; ++kt)
                Bf[ngl][kt] = __builtin_bit_cast(bf16x8, pb[(kt * 17 + (h * 4 + half * 2 + ngl)) * 64 + l]);
        bf16x8 Bfe[4];
        if (w == 0) {
            #pragma unroll
            for (int kt = 0; kt < 4; ++kt)
                Bfe[kt] = __builtin_bit_cast(bf16x8, pb[(kt * 17 + 16) * 64 + l]);
        }
        #pragma unroll
        for (int m = 0; m < 3; ++m) {
            int r = m * 16 + l15, abase = (r << 8) + (lq << 4), swz = (r & 7) << 4;
            bf16x8 Af[4];
            #pragma unroll
            for (int kt = 0; kt < 4; ++kt)
                Af[kt] = *(const bf16x8*)(R0 + ((abase + (kt << 6)) ^ swz));
            f32x4 acc[2];
            #pragma unroll
            for (int ngl = 0; ngl < 2; ++ngl) acc[ngl] = (f32x4){0.f, 0.f, 0.f, 0.f};
            #pragma unroll
            for (int ngl = 0; ngl < 2; ++ngl)
                #pragma unroll
                for (int kt = 0; kt < 4; ++kt)
                    acc[ngl] = __builtin_amdgcn_mfma_f32_16x16x32_bf16(Af[kt], Bf[ngl][kt], acc[ngl], 0, 0, 0);
            int row0 = m * 16 + lq * 4;
            #pragma unroll
            for (int ngl = 0; ngl < 2; ++ngl) {            // packed b64 store (4 consecutive rows)
                int col = h * 64 + (half * 2 + ngl) * 16 + l15;
                unsigned q0 = (unsigned)f2bf(acc[ngl][0]) | ((unsigned)f2bf(acc[ngl][1]) << 16);
                unsigned q1 = (unsigned)f2bf(acc[ngl][2]) | ((unsigned)f2bf(acc[ngl][3]) << 16);
                int addr = ((col << 7) + (row0 << 1)) ^ ((col & 7) << 4);
                *(uint2*)(R1 + addr) = make_uint2(q0, q1);
            }
            if (w == 0) {
                f32x4 acce = (f32x4){0.f, 0.f, 0.f, 0.f};
                #pragma unroll
                for (int kt = 0; kt < 4; ++kt)
                    acce = __builtin_amdgcn_mfma_f32_16x16x32_bf16(Af[kt], Bfe[kt], acce, 0, 0, 0);
                if (l15 < 8) {
                    #pragma unroll
                    for (int reg = 0; reg < 4; ++reg) {
                        int row = row0 + reg;
                        if (l15 < 4) eS1[row][l15] = acce[reg];
                        else         eD1[row][l15 - 4] = acce[reg];
                    }
                }
            }
        }
    }
    __syncthreads();

    // ---- P2: softmax1 -> alpha1[h][i][j] bf16, packed uint2 writes
    if (t < 192) {
        int g = t / 48, rem = t % 48, i = rem >> 2, h = rem & 3;
        int rowi = g * 12 + i;
        float edi = eD1[rowi][h];
        float lv[12]; float mx = -1e30f;
        #pragma unroll
        for (int j = 0; j < 12; ++j) {
            float v = lrelu(edi + eS1[g * 12 + j][h]);
            lv[j] = v; mx = fmaxf(mx, v);
        }
        float s = 0.f;
        #pragma unroll
        for (int j = 0; j < 12; ++j) { lv[j] = __expf(lv[j] - mx); s += lv[j]; }
        float inv = 1.f / s;
        unsigned char* base = R2 + h * 6144;
        int rb = rowi << 7, swz = (rowi & 7) << 4, ob = g * 24;
        #pragma unroll
        for (int p = 0; p < 3; ++p) {
            unsigned q0 = (unsigned)f2bf(lv[4*p]   * inv) | ((unsigned)f2bf(lv[4*p+1] * inv) << 16);
            unsigned q1 = (unsigned)f2bf(lv[4*p+2] * inv) | ((unsigned)f2bf(lv[4*p+3] * inv) << 16);
            int addr = (rb + ob + p * 8) ^ swz;
            *(uint2*)(base + addr) = make_uint2(q0, q1);
        }
    }
    __syncthreads();

    // ---- P3: aggregation1 via MFMA + bias + ELU -> x2 (overlays alpha1)
    //      wave pair shares head region: preload ALL alpha A-frags, barrier,
    //      then MFMA+store (cross-wave read-before-write).
    {
        const int h = w >> 1, half = w & 1;
        bf16x8 Bh[2][2];
        #pragma unroll
        for (int kt = 0; kt < 2; ++kt)
            #pragma unroll
            for (int ntl = 0; ntl < 2; ++ntl) {
                int col = h * 64 + (half * 2 + ntl) * 16 + l15;
                int addr = ((col << 7) + (kt << 6) + (lq << 4)) ^ ((col & 7) << 4);
                Bh[kt][ntl] = *(const bf16x8*)(R1 + addr);
            }
        float b1v[2];
        #pragma unroll
        for (int ntl = 0; ntl < 2; ++ntl) b1v[ntl] = b1[h * 64 + (half * 2 + ntl) * 16 + l15];
        unsigned char* aab = R2 + h * 6144;
        bf16x8 Aa[3][2];
        #pragma unroll
        for (int m = 0; m < 3; ++m) {
            int r = m * 16 + l15, swz = (r & 7) << 4;
            #pragma unroll
            for (int kt = 0; kt < 2; ++kt)
                Aa[m][kt] = *(const bf16x8*)(aab + (((r << 7) + (kt << 6) + (lq << 4)) ^ swz));
        }
        __syncthreads();                                   // all alpha read before any x2 write
        #pragma unroll
        for (int m = 0; m < 3; ++m) {
            #pragma unroll
            for (int ntl = 0; ntl < 2; ++ntl) {
                f32x4 acc = (f32x4){0.f, 0.f, 0.f, 0.f};
                #pragma unroll
                for (int kt = 0; kt < 2; ++kt)
                    acc = __builtin_amdgcn_mfma_f32_16x16x32_bf16(Aa[m][kt], Bh[kt][ntl], acc, 0, 0, 0);
                #pragma unroll
                for (int reg = 0; reg < 4; ++reg) {
                    int row = m * 16 + lq * 4 + reg;
                    float val = elu1(acc[reg] + b1v[ntl]);
                    int addr = ((row << 7) + (((half * 2 + ntl) * 16 + l15) << 1)) ^ ((row & 7) << 4);
                    *(unsigned short*)(aab + addr) = f2bf(val);
                }
            }
        }
    }
    __syncthreads();

    // ---- P4: GEMM2 (x2 @ [W2 | va2]) -> h2T bf16 + eS2/eD2; zero pads
    //      15 (tile, m) units over 8 waves: wave w handles units {2w, 2w+1}
    {
        if (t < 128) {                                     // zero h2T rows 48..63
            int col = t >> 1, bs = 6 + (t & 1);
            int addr = ((col << 7) + (bs << 4)) ^ ((col & 7) << 4);
            *(uint4*)(R1 + addr) = make_uint4(0, 0, 0, 0);
        }
        if (t < 192) {                                     // zero alpha2 (6144 B)
            *(uint4*)(R1 + 8192 + (t << 4)) = make_uint4(0, 0, 0, 0);
            *(uint4*)(R1 + 8192 + ((t + 192) << 4)) = make_uint4(0, 0, 0, 0);
        }
        const uint4* pb2 = (const uint4*)wsB2;
        #pragma unroll
        for (int ui = 0; ui < 2; ++ui) {
            int u = w * 2 + ui;
            if (u < 15) {
                int tile = u / 3, m = u % 3;
                bf16x8 Bg[8];
                #pragma unroll
                for (int kt = 0; kt < 8; ++kt)
                    Bg[kt] = __builtin_bit_cast(bf16x8, pb2[(kt * 5 + tile) * 64 + l]);
                int r = m * 16 + l15, swz = (r & 7) << 4;
                f32x4 acc = (f32x4){0.f, 0.f, 0.f, 0.f};
                #pragma unroll
                for (int kt = 0; kt < 8; ++kt) {
                    int addr = (kt >> 1) * 6144 + (((r << 7) + ((kt & 1) << 6) + (lq << 4)) ^ swz);
                    bf16x8 Ax = *(const bf16x8*)(R2 + addr);
                    acc = __builtin_amdgcn_mfma_f32_16x16x32_bf16(Ax, Bg[kt], acc, 0, 0, 0);
                }
                int row0 = m * 16 + lq * 4;
                if (tile < 4) {
                    int col = tile * 16 + l15;
                    unsigned q0 = (unsigned)f2bf(acc[0]) | ((unsigned)f2bf(acc[1]) << 16);
                    unsigned q1 = (unsigned)f2bf(acc[2]) | ((unsigned)f2bf(acc[3]) << 16);
                    int addr = ((col << 7) + (row0 << 1)) ^ ((col & 7) << 4);
                    *(uint2*)(R1 + addr) = make_uint2(q0, q1);
                } else if (l15 < 2) {                      // e-tile
                    #pragma unroll
                    for (int reg = 0; reg < 4; ++reg) {
                        int row = row0 + reg;
                        if (l15 == 0) eS2[row] = acc[reg];
                        else          eD2[row] = acc[reg];
                    }
                }
            }
        }
    }
    __syncthreads();

    // ---- P5: softmax2 -> alpha2[i][j] bf16, packed uint2 writes
    if (t < 48) {
        int g = t / 12;
        float edi = eD2[t];
        float lv[12]; float mx = -1e30f;
        #pragma unroll
        for (int j = 0; j < 12; ++j) {
            float v = lrelu(edi + eS2[g * 12 + j]);
            lv[j] = v; mx = fmaxf(mx, v);
        }
        float s = 0.f;
        #pragma unroll
        for (int j = 0; j < 12; ++j) { lv[j] = __expf(lv[j] - mx); s += lv[j]; }
        float inv = 1.f / s;
        int rb = t << 7, swz = (t & 7) << 4, ob = g * 24;
        #pragma unroll
        for (int p = 0; p < 3; ++p) {
            unsigned q0 = (unsigned)f2bf(lv[4*p]   * inv) | ((unsigned)f2bf(lv[4*p+1] * inv) << 16);
            unsigned q1 = (unsigned)f2bf(lv[4*p+2] * inv) | ((unsigned)f2bf(lv[4*p+3] * inv) << 16);
            int addr = 8192 + ((rb + ob + p * 8) ^ swz);
            *(uint2*)(R1 + addr) = make_uint2(q0, q1);
        }
    }
    __syncthreads();

    // ---- P6: aggregation2 via MFMA + bias + ELU -> x3 f32 (overlays R0)
    //      waves 0..3: o-tile w, m in {0,1}; waves 4..7: o-tile w-4, m=2
    {
        const int otile = w & 3;
        bf16x8 Bh2[2];
        int col = otile * 16 + l15;
        #pragma unroll
        for (int kt = 0; kt < 2; ++kt) {
            int addr = ((col << 7) + (kt << 6) + (lq << 4)) ^ ((col & 7) << 4);
            Bh2[kt] = *(const bf16x8*)(R1 + addr);
        }
        float b2v = b2[col];
        const int m0 = (w < 4) ? 0 : 2, mcount = (w < 4) ? 2 : 1;
        for (int mi = 0; mi < mcount; ++mi) {
            int m = m0 + mi;
            int r = m * 16 + l15, swz = (r & 7) << 4;
            f32x4 acc = (f32x4){0.f, 0.f, 0.f, 0.f};
            #pragma unroll
            for (int kt = 0; kt < 2; ++kt) {
                bf16x8 Aa = *(const bf16x8*)(R1 + 8192 + (((r << 7) + (kt << 6) + (lq << 4)) ^ swz));
                acc = __builtin_amdgcn_mfma_f32_16x16x32_bf16(Aa, Bh2[kt], acc, 0, 0, 0);
            }
            #pragma unroll
            for (int reg = 0; reg < 4; ++reg) {
                int row = m * 16 + lq * 4 + reg;
                *(float*)(R0 + row * 272 + (col << 2)) = elu1(acc[reg] + b2v);
            }
        }
    }
    __syncthreads();

    // ---- pool (first 4 waves)
    if (t < 256) {
        int o = t & 63, g = t >> 6;
        float s = 0.f;
        #pragma unroll
        for (int j = 0; j < 12; ++j)
            s += *(const float*)(R0 + (g * 12 + j) * 272 + (o << 2));
        gpool[g][o] = s * (1.0f / 12.0f);
    }
    __syncthreads();

    // ---- classifier 64 -> 32 (relu) -> 1
    if (t < 128) {
        int g = t >> 5, nr = t & 31;
        float acc = bc1[nr];
        #pragma unroll
        for (int cc = 0; cc < 64; ++cc)
            acc = fmaf(gpool[g][cc], Wc1[cc * 32 + nr], acc);
        float val = fmaxf(acc, 0.f) * Wc2[nr];
        #pragma unroll
        for (int msk = 1; msk < 32; msk <<= 1) val += __shfl_xor(val, msk);
        if (nr == 0) out[b * 4 + g] = val + bc2[0];
    }
}

// ---------------------------------------------------------------------------
// f32 fallback — used only if ws too small or B % 4 != 0
// ---------------------------------------------------------------------------
__global__ __launch_bounds__(256, 4) void gat_fused_f32(
    const float* __restrict__ x_in, const float* __restrict__ W1,
    const float* __restrict__ a_src1, const float* __restrict__ a_dst1,
    const float* __restrict__ b1, const float* __restrict__ W2,
    const float* __restrict__ a_src2, const float* __restrict__ a_dst2,
    const float* __restrict__ b2, const float* __restrict__ Wc1,
    const float* __restrict__ bc1, const float* __restrict__ Wc2,
    const float* __restrict__ bc2, float* __restrict__ out)
{
    __shared__ union {
        float x_l[NN][FIN];
        struct { float h2[NN][C2]; float x3[NN][C2]; } s2;
    } u;
    __shared__ float h1s[NN][D1];
    __shared__ float x2s[NN][D1];
    __shared__ float alpha1[NN][NN][4];
    __shared__ float e_s1[NN][4], e_d1[NN][4];
    __shared__ float e_s2[NN], e_d2[NN];
    __shared__ float alpha2[NN][NN];
    __shared__ float gph[C2];
    __shared__ float hdn[32];

    const int b = blockIdx.x, t = threadIdx.x;
    const float* xb = x_in + (size_t)b * (NN * FIN);
    for (int i = t; i < NN * FIN; i += 256) (&u.x_l[0][0])[i] = xb[i];
    __syncthreads();
    {
        const int o0 = (t & 127) * 2, n0 = (t >> 7) * 6;
        float acc[6][2];
        #pragma unroll
        for (int i = 0; i < 6; ++i) { acc[i][0] = 0.f; acc[i][1] = 0.f; }
        for (int f = 0; f < FIN; f += 4) {
            float4 xv[6];
            #pragma unroll
            for (int i = 0; i < 6; ++i) xv[i] = *(const float4*)&u.x_l[n0 + i][f];
            #pragma unroll
            for (int k = 0; k < 4; ++k) {
                const float2 wv = *(const float2*)&W1[(f + k) * D1 + o0];
                #pragma unroll
                for (int i = 0; i < 6; ++i) {
                    const float xs = ((const float*)&xv[i])[k];
                    acc[i][0] = fmaf(xs, wv.x, acc[i][0]);
                    acc[i][1] = fmaf(xs, wv.y, acc[i][1]);
                }
            }
        }
        #pragma unroll
        for (int i = 0; i < 6; ++i) { h1s[n0+i][o0] = acc[i][0]; h1s[n0+i][o0+1] = acc[i][1]; }
    }
    __syncthreads();
    if (t < NN * 4) {
        const int n = t >> 2, h = t & 3;
        float es = 0.f, ed = 0.f;
        for (int c = 0; c < 64; ++c) {
            const float v = h1s[n][h * 64 + c];
            es = fmaf(v, a_src1[h * 64 + c], es);
            ed = fmaf(v, a_dst1[h * 64 + c], ed);
        }
        e_s1[n][h] = es; e_d1[n][h] = ed;
    }
    __syncthreads();
    if (t < NN * 4) {
        const int i = t >> 2, h = t & 3;
        const float edi = e_d1[i][h];
        float lv[NN]; float m = -1e30f;
        #pragma unroll
        for (int j = 0; j < NN; ++j) {
            float v = edi + e_s1[j][h]; v = v > 0.f ? v : SLOPE * v;
            lv[j] = v; m = fmaxf(m, v);
        }
        float s = 0.f;
        #pragma unroll
        for (int j = 0; j < NN; ++j) { lv[j] = __expf(lv[j] - m); s += lv[j]; }
        const float inv = 1.f / s;
        #pragma unroll
        for (int j = 0; j < NN; ++j) alpha1[i][j][h] = lv[j] * inv;
    }
    __syncthreads();
    {
        const int o = t, h = o >> 6;
        const float bo = b1[o];
        float v[NN];
        #pragma unroll
        for (int j = 0; j < NN; ++j) v[j] = h1s[j][o];
        #pragma unroll
        for (int i = 0; i < NN; ++i) {
            float acc = 0.f;
            #pragma unroll
            for (int j = 0; j < NN; ++j) acc = fmaf(alpha1[i][j][h], v[j], acc);
            x2s[i][o] = acc + bo > 0.f ? acc + bo : expm1f(acc + bo);
        }
    }
    __syncthreads();
    {
        const int c = t & 63, n0 = (t >> 6) * 3;
        float acc[3] = {0.f, 0.f, 0.f};
        for (int f = 0; f < D1; f += 4) {
            float4 xv[3];
            #pragma unroll
            for (int i = 0; i < 3; ++i) xv[i] = *(const float4*)&x2s[n0 + i][f];
            #pragma unroll
            for (int k = 0; k < 4; ++k) {
                const float wv = W2[(f + k) * C2 + c];
                #pragma unroll
                for (int i = 0; i < 3; ++i) acc[i] = fmaf(((const float*)&xv[i])[k], wv, acc[i]);
            }
        }
        #pragma unroll
        for (int i = 0; i < 3; ++i) u.s2.h2[n0 + i][c] = acc[i];
    }
    __syncthreads();
    if (t < NN) {
        float es = 0.f, ed = 0.f;
        for (int c = 0; c < 64; c += 4) {
            const float4 v  = *(const float4*)&u.s2.h2[t][c];
            const float4 as = *(const float4*)&a_src2[c];
            const float4 ad = *(const float4*)&a_dst2[c];
            es += v.x*as.x + v.y*as.y + v.z*as.z + v.w*as.w;
            ed += v.x*ad.x + v.y*ad.y + v.z*ad.z + v.w*ad.w;
        }
        e_s2[t] = es; e_d2[t] = ed;
    }
    __syncthreads();
    if (t < NN) {
        const float edi = e_d2[t];
        float lv[NN]; float m = -1e30f;
        #pragma unroll
        for (int j = 0; j < NN; ++j) {
            float v = edi + e_s2[j]; v = v > 0.f ? v : SLOPE * v;
            lv[j] = v; m = fmaxf(m, v);
        }
        float s = 0.f;
        #pragma unroll
        for (int j = 0; j < NN; ++j) { lv[j] = __expf(lv[j] - m); s += lv[j]; }
        const float inv = 1.f / s;
        #pragma unroll
        for (int j = 0; j < NN; ++j) alpha2[t][j] = lv[j] * inv;
    }
    __syncthreads();
    {
        const int c = t & 63, i0 = (t >> 6) * 3;
        float v[NN];
        #pragma unroll
        for (int j = 0; j < NN; ++j) v[j] = u.s2.h2[j][c];
        const float bc = b2[c];
        #pragma unroll
        for (int ii = 0; ii < 3; ++ii) {
            const int i = i0 + ii;
            float acc = 0.f;
            #pragma unroll
            for (int j = 0; j < NN; ++j) acc = fmaf(alpha2[i][j], v[j], acc);
            u.s2.x3[i][c] = acc + bc > 0.f ? acc + bc : expm1f(acc + bc);
        }
    }
    __syncthreads();
    if (t < C2) {
        float s = 0.f;
        #pragma unroll
        for (int i = 0; i < NN; ++i) s += u.s2.x3[i][t];
        gph[t] = s * (1.0f / NN);
    }
    __syncthreads();
    if (t < 32) {
        float acc = bc1[t];
        for (int c = 0; c < C2; ++c) acc = fmaf(gph[c], Wc1[c * 32 + t], acc);
        hdn[t] = fmaxf(acc, 0.f);
    }
    __syncthreads();
    if (t == 0) {
        float acc = bc2[0];
        #pragma unroll
        for (int k = 0; k < 32; ++k) acc = fmaf(hdn[k], Wc2[k], acc);
        out[b] = acc;
    }
}

extern "C" void kernel_launch(void* const* d_in, const int* in_sizes, int n_in,
                              void* d_out, int out_size, void* d_ws, size_t ws_size,
                              hipStream_t stream) {
    const float* x   = (const float*)d_in[0];
    const float* W1  = (const float*)d_in[1];
    const float* as1 = (const float*)d_in[2];
    const float* ad1 = (const float*)d_in[3];
    const float* b1  = (const float*)d_in[4];
    const float* W2  = (const float*)d_in[5];
    const float* as2 = (const float*)d_in[6];
    const float* ad2 = (const float*)d_in[7];
    const float* b2  = (const float*)d_in[8];
    const float* Wc1 = (const float*)d_in[9];
    const float* bc1 = (const float*)d_in[10];
    const float* Wc2 = (const float*)d_in[11];
    const float* bc2 = (const float*)d_in[12];
    float* out = (float*)d_out;

    const int B = in_sizes[0] / (NN * FIN);

    if (ws_size >= 110592 && (B % 4) == 0) {
        unsigned short* wsB1 = (unsigned short*)d_ws;
        unsigned short* wsB2 = wsB1 + 34816;
        prep_weights<<<216, 256, 0, stream>>>(W1, as1, ad1, W2, as2, ad2, wsB1, wsB2);
        gat_mfma6<<<B / 4, 512, 0, stream>>>(x, wsB1, wsB2, b1, b2, Wc1, bc1, Wc2, bc2, out);
    } else {
        gat_fused_f32<<<B, 256, 0, stream>>>(x, W1, as1, ad1, b1, W2, as2, ad2, b2,
                                             Wc1, bc1, Wc2, bc2, out);
    }
}